// Round 8
// baseline (1828.220 us; speedup 1.0000x reference)
//
#include <hip/hip_runtime.h>
#include <cmath>

#define WGS  256
#define NWGR 256         // recurrence workgroups (1 per CU)
#define DOMS 4           // independent batch domains (8 batches each)
#define JGN  64          // j-groups per domain (8 j each)
#define HBDW 5120        // dwords per parity buffer per domain (64 blocks x 80)

typedef float    f32x4 __attribute__((ext_vector_type(4)));
typedef unsigned u32x4 __attribute__((ext_vector_type(4)));
typedef short    s16x8 __attribute__((ext_vector_type(8)));
typedef unsigned short u16x4 __attribute__((ext_vector_type(4)));

// ---------------- sizes ----------------
#define B_   32
#define S_   200
#define L_   50
#define H_   512
#define DE_  256
#define VS_  30000
#define TD_  49          // L-1 decoder steps
#define G3_  1536        // 3*H

// ws layout (float offsets)
#define OFF_ENC_GX  ((size_t)0)                         // [200][32][1536]
#define SZ_ENC_GX   ((size_t)S_*B_*G3_)
#define OFF_DEC_GX  (OFF_ENC_GX + SZ_ENC_GX)            // [49][32][1536]
#define SZ_DEC_GX   ((size_t)TD_*B_*G3_)
#define OFF_ENC_OUT (OFF_DEC_GX + SZ_DEC_GX)            // [32][200][512]
#define SZ_ENC_OUT  ((size_t)B_*S_*H_)
#define OFF_HBUF    (OFF_ENC_OUT + SZ_ENC_OUT)          // [dom4][buf2][5120] tagged
#define SZ_HBUF     ((size_t)DOMS*2*HBDW)               // 40960 floats
#define OFF_CMAT    (OFF_HBUF + SZ_HBUF)                // [49][32][1024]
#define SZ_CMAT     ((size_t)TD_*B_*2*H_)
#define OFF_OUT1    (OFF_CMAT + SZ_CMAT)                // [1568][512]
#define SZ_OUT1     ((size_t)TD_*B_*H_)
// bf16 split overlays (active only AFTER recurrence+attention have consumed
// enc_gx/dec_gx/enc_out/hbuf): W2hi/W2lo = 2 x 15.36M ushort = 15.36M floats,
// which fits inside [0, OFF_CMAT) = 15.55M floats. OUT1 splits go after OUT1.
#define OFF_W2HI    ((size_t)0)                         // ushort[VS_*H_]
#define OFF_W2LO    ((size_t)(VS_*H_/2))                // float offset 7.68M
#define OFF_O1HI    (OFF_OUT1 + SZ_OUT1)                // ushort[TD_*B_*H_]
#define OFF_O1LO    (OFF_O1HI + (size_t)(TD_*B_*H_/2))

// LDS geometry: k-blocks of 64 floats @ stride 68 (<=2-way conflicts)
#define RSTR 548
#define KBLK 68

__device__ __forceinline__ u32x4 load_u4_cc(const unsigned* p) {
  u32x4 v;
  asm volatile("global_load_dwordx4 %0, %1, off sc0 sc1" : "=v"(v) : "v"(p) : "memory");
  return v;
}

__device__ __forceinline__ float dot4(f32x4 a, f32x4 b) {
  return a.x * b.x + a.y * b.y + a.z * b.z + a.w * b.w;
}

// bf16 round-to-nearest-even via bit manipulation (no header dependence)
__device__ __forceinline__ unsigned short f2bf(float f) {
  unsigned u = __float_as_uint(f);
  return (unsigned short)((u + 0x7fffu + ((u >> 16) & 1u)) >> 16);
}
__device__ __forceinline__ float bf2f(unsigned short h) {
  return __uint_as_float(((unsigned)h) << 16);
}

// ---------------- persistent GRU-chain kernel, barrier-free ----------------
// 256 WGs: dom = w>>6 (8 batches), jg = w&63 (8 j-values). Weights in VGPRs.
// Thread: jl = t&7 (j), kh = t>>3 (k-chunk of 16). Tail t<64: jl=t&7, bt=t>>3.
// Exchange block (per jg): 80 dwords = 5 cachelines; tag at pos%16==0, payload
// p = pos-1-pos/16 (p<64), p=(b<<3)+jl. Published by exactly 2 wave-store
// instructions -> each 64B line written whole -> tag+payload atomic at L3.
__global__ __launch_bounds__(WGS)
void recurrence_kernel(const float* __restrict__ enc_gx,
                       const float* __restrict__ dec_gx,
                       const float* __restrict__ eWhh, const float* __restrict__ eBhh,
                       const float* __restrict__ dWhh, const float* __restrict__ dBhh,
                       float* __restrict__ enc_out,
                       float* __restrict__ hbuf,
                       float* __restrict__ Cmat)
{
  __shared__ float hlds[8 * RSTR];    // 17536 B: 8 batches x 512 k
  __shared__ float red[768];          //  3072 B: [wave4][jl8][g3][b8]

  const int t   = threadIdx.x;
  const int w   = blockIdx.x;
  const int dom = w >> 6;
  const int jg  = w & (JGN - 1);
  const int jl  = t & 7;
  const int kh  = t >> 3;             // 0..31 (compute role)
  const int bt_ = t >> 3;             // 0..7  (tail role, t<64)
  const int j   = (jg << 3) + jl;
  const int b_g = (dom << 3) + bt_;

  float* hdom = hbuf + (size_t)dom * (2 * HBDW);

  // staging constants: 5 dwordx4 loads; rr = dword offset within 80-dw block
  int rr[5], kb[5];
  #pragma unroll
  for (int i = 0; i < 5; ++i) {
    int g = i * 1024 + (t << 2);
    int blk = g / 80;
    rr[i] = g - blk * 80;
    kb[i] = blk << 3;                 // k base of the block
  }

  // weights in VGPRs: wreg[gate][k-subchunk], k = kh*16 + c*4 + lane-of-4
  f32x4 wreg[3][4];
  auto load_w = [&](const float* __restrict__ W) {
    #pragma unroll
    for (int g = 0; g < 3; ++g)
      #pragma unroll
      for (int c = 0; c < 4; ++c)
        wreg[g][c] = *(const f32x4*)(W + (size_t)(g * H_ + j) * H_ + (kh << 4) + (c << 2));
  };
  load_w(eWhh);

  float bias_r = 0.f, bias_z = 0.f, bias_n = 0.f;
  if (t < 64) { bias_r = eBhh[j]; bias_z = eBhh[H_ + j]; bias_n = eBhh[2 * H_ + j]; }

  for (int s = 0; s < S_ + TD_; ++s) {
    const bool enc = (s < S_);
    __syncthreads();    // hlds/red from prev step fully consumed
    if (s == S_) {      // switch to decoder weights
      load_w(dWhh);
      if (t < 64) { bias_r = dBhh[j]; bias_z = dBhh[H_ + j]; bias_n = dBhh[2 * H_ + j]; }
    }

    // gx for the tail (normal cached loads, issued early)
    float gxr = 0.f, gxz = 0.f, gxn = 0.f;
    if (t < 64) {
      const float* gx = enc ? (enc_gx + ((size_t)s * B_ + b_g) * G3_)
                            : (dec_gx + ((size_t)(s - S_) * B_ + b_g) * G3_);
      gxr = gx[j]; gxz = gx[H_ + j]; gxn = gx[2 * H_ + j];
    }

    // ---- stage h_s: poll tagged lines until fresh, scatter to LDS ----
    {
      const unsigned* hb = (const unsigned*)(hdom + (size_t)(s & 1) * HBDW);
      const unsigned tagreq = (unsigned)s;
      u32x4 v0, v1, v2, v3, v4;
      while (true) {
        v0 = load_u4_cc(hb + 0 * 1024 + (t << 2));
        v1 = load_u4_cc(hb + 1 * 1024 + (t << 2));
        v2 = load_u4_cc(hb + 2 * 1024 + (t << 2));
        v3 = load_u4_cc(hb + 3 * 1024 + (t << 2));
        v4 = load_u4_cc(hb + 4 * 1024 + (t << 2));
        asm volatile("s_waitcnt vmcnt(0)" ::: "memory");
        bool ok = true;
        if ((rr[0] & 15) == 0) ok &= ((unsigned)v0.x >= tagreq);
        if ((rr[1] & 15) == 0) ok &= ((unsigned)v1.x >= tagreq);
        if ((rr[2] & 15) == 0) ok &= ((unsigned)v2.x >= tagreq);
        if ((rr[3] & 15) == 0) ok &= ((unsigned)v3.x >= tagreq);
        if ((rr[4] & 15) == 0) ok &= ((unsigned)v4.x >= tagreq);
        if (__all(ok)) break;
        __builtin_amdgcn_s_sleep(1);
      }
      #define SCAT(vv, ii) { \
        _Pragma("unroll") \
        for (int d = 0; d < 4; ++d) { \
          int pos = rr[ii] + d; \
          if ((pos & 15) != 0) { \
            int p = pos - 1 - (pos >> 4); \
            if (p < 64) { \
              int bb = p >> 3, k = kb[ii] + (p & 7); \
              hlds[bb * RSTR + ((k >> 6) * KBLK) + (k & 63)] = __uint_as_float(vv[d]); \
            } } } }
      SCAT(v0, 0) SCAT(v1, 1) SCAT(v2, 2) SCAT(v3, 3) SCAT(v4, 4)
      #undef SCAT
    }
    __syncthreads();

    // ---- compute: 8 j x 3 gates, 16-k slice per thread, all 8 batches ----
    float acc[3][8];
    #pragma unroll
    for (int g = 0; g < 3; ++g)
      #pragma unroll
      for (int b = 0; b < 8; ++b) acc[g][b] = 0.f;

    const int hoff = (kh >> 2) * KBLK + ((kh & 3) << 4);
    #pragma unroll
    for (int b = 0; b < 8; ++b) {
      const float* hp = &hlds[b * RSTR + hoff];
      f32x4 h0 = *(const f32x4*)(hp);
      f32x4 h1 = *(const f32x4*)(hp + 4);
      f32x4 h2 = *(const f32x4*)(hp + 8);
      f32x4 h3 = *(const f32x4*)(hp + 12);
      #pragma unroll
      for (int g = 0; g < 3; ++g)
        acc[g][b] += dot4(wreg[g][0], h0) + dot4(wreg[g][1], h1)
                   + dot4(wreg[g][2], h2) + dot4(wreg[g][3], h3);
    }

    // fold kh within wave (kh bits 0..2 = t bits 3..5)
    #pragma unroll
    for (int g = 0; g < 3; ++g)
      #pragma unroll
      for (int b = 0; b < 8; ++b) {
        float v = acc[g][b];
        v += __shfl_xor(v, 8);
        v += __shfl_xor(v, 16);
        v += __shfl_xor(v, 32);
        acc[g][b] = v;
      }
    if ((t & 56) == 0) {                      // one lane per (wave, jl)
      const int base = ((t >> 6) * 8 + jl) * 24;
      #pragma unroll
      for (int g = 0; g < 3; ++g)
        #pragma unroll
        for (int b = 0; b < 8; ++b)
          red[base + g * 8 + b] = acc[g][b];
    }
    __syncthreads();

    // ---- tail (wave 0): combine 4 wave-partials, gate math, publish ----
    if (t < 64) {
      float ar = 0.f, az = 0.f, an = 0.f;
      #pragma unroll
      for (int ww = 0; ww < 4; ++ww) {
        const int base = (ww * 8 + jl) * 24;
        ar += red[base + bt_];
        az += red[base + 8 + bt_];
        an += red[base + 16 + bt_];
      }
      float rg = 1.f / (1.f + expf(-(gxr + ar + bias_r)));
      float zg = 1.f / (1.f + expf(-(gxz + az + bias_z)));
      float ng = tanhf(gxn + rg * (an + bias_n));
      float hprev = hlds[bt_ * RSTR + ((j >> 6) * KBLK) + (j & 63)];
      float hn = (1.f - zg) * ng + zg * hprev;
      if (enc) enc_out[((size_t)b_g * S_ + s) * H_ + j] = hn;
      else     Cmat[((size_t)(s - S_) * B_ + b_g) * (2 * H_) + H_ + j] = hn;

      // publish h_{s+1}: payload index p == tail thread index
      unsigned* pb = (unsigned*)(hdom + (size_t)((s + 1) & 1) * HBDW) + jg * 80;
      const unsigned tagv = (unsigned)(s + 1);
      // store A: lines 0-3 (dwords 0..63)
      float vA = __shfl(hn, (t - 1 - (t >> 4)) & 63);
      unsigned valA = ((t & 15) == 0) ? tagv : __float_as_uint(vA);
      __hip_atomic_store(pb + t, valA, __ATOMIC_RELAXED, __HIP_MEMORY_SCOPE_AGENT);
      // store B: line 4 (dwords 64..79; payloads p=60..63 at pos 65..68)
      float vB = __shfl(hn, (59 + t) & 63);
      if (t < 16) {
        unsigned valB = (t == 0) ? tagv : __float_as_uint(vB);
        __hip_atomic_store(pb + 64 + t, valB, __ATOMIC_RELAXED, __HIP_MEMORY_SCOPE_AGENT);
      }
    }
  }
}

// ---------------- attention kernel: one WG per (td, b) ----------------
__global__ __launch_bounds__(WGS)
void attention_kernel(const float* __restrict__ enc_out,
                      float* __restrict__ Cmat)
{
  const int task = blockIdx.x;          // td*32 + b
  const int td = task >> 5, b = task & 31;
  const int t = threadIdx.x;
  const float* h = Cmat + ((size_t)td * B_ + b) * (2 * H_) + H_;

  __shared__ float red[WGS];
  __shared__ float p[WGS];              // 200 used

  float sv = -1e30f;
  if (t < S_) {
    const float* eo = enc_out + ((size_t)b * S_ + t) * H_;
    float acc = 0.f;
    #pragma unroll 4
    for (int k = 0; k < H_; k += 4) {
      float4 e = *(const float4*)(eo + k);
      float4 hv = *(const float4*)(h + k);
      acc += e.x * hv.x + e.y * hv.y + e.z * hv.z + e.w * hv.w;
    }
    sv = acc;
  }
  red[t] = sv; __syncthreads();
  for (int o = 128; o; o >>= 1) { if (t < o) red[t] = fmaxf(red[t], red[t + o]); __syncthreads(); }
  float mx = red[0]; __syncthreads();
  float ev = (t < S_) ? expf(sv - mx) : 0.f;
  red[t] = ev; __syncthreads();
  for (int o = 128; o; o >>= 1) { if (t < o) red[t] += red[t + o]; __syncthreads(); }
  float inv = 1.f / red[0];
  p[t] = ev * inv;
  __syncthreads();

  const float* eo = enc_out + (size_t)b * S_ * H_ + (t << 1);
  float ax = 0.f, ay = 0.f;
  for (int i = 0; i < S_; ++i) {
    float pi = p[i];
    float2 v = *(const float2*)(eo + (size_t)i * H_);
    ax += pi * v.x; ay += pi * v.y;
  }
  float* cd = Cmat + ((size_t)td * B_ + b) * (2 * H_) + (t << 1);
  cd[0] = ax; cd[1] = ay;
}

// ---------------- tiled fp32 GEMM 64x64 (modes 0/1/2) ----------------
template<int MODE>
__launch_bounds__(WGS)
__global__ void gemm_bt(const float* __restrict__ A,
                        const int* __restrict__ idx,
                        const float* __restrict__ Bw,
                        const float* __restrict__ bias,
                        float* __restrict__ Cdst,
                        int M, int N, int K)
{
  const int BM = 64, BN = 64, BK = 16;
  __shared__ float As[BK][BM];
  __shared__ float Bs[BK][BN];
  __shared__ int toks[BM];
  const int m0 = blockIdx.y * BM, n0 = blockIdx.x * BN;
  const int t = threadIdx.x;
  const int tx = t & 15, ty = t >> 4;
  float acc[4][4] = {{0.f}};

  if (MODE <= 1) {
    if (t < BM) {
      int m = m0 + t;
      int tok = 0;
      if (m < M) {
        int bidx = m & 31, srow = m >> 5;
        tok = (MODE == 0) ? idx[bidx * S_ + srow] : idx[bidx * L_ + srow];
      }
      toks[t] = tok;
    }
    __syncthreads();
  }

  const int row = t >> 2, kk = (t & 3) * 4;
  for (int k0 = 0; k0 < K; k0 += BK) {
    {
      int m = m0 + row;
      float4 v = {0.f, 0.f, 0.f, 0.f};
      if (m < M) {
        const float* src = (MODE <= 1) ? (A + (size_t)toks[row] * K + k0 + kk)
                                       : (A + (size_t)m * K + k0 + kk);
        v = *(const float4*)src;
      }
      As[kk][row] = v.x; As[kk + 1][row] = v.y; As[kk + 2][row] = v.z; As[kk + 3][row] = v.w;
      int n = n0 + row;
      float4 wv = {0.f, 0.f, 0.f, 0.f};
      if (n < N) wv = *(const float4*)(Bw + (size_t)n * K + k0 + kk);
      Bs[kk][row] = wv.x; Bs[kk + 1][row] = wv.y; Bs[kk + 2][row] = wv.z; Bs[kk + 3][row] = wv.w;
    }
    __syncthreads();
    #pragma unroll
    for (int k = 0; k < BK; ++k) {
      float a[4], bq[4];
      *(float4*)a  = *(const float4*)&As[k][ty * 4];
      *(float4*)bq = *(const float4*)&Bs[k][tx * 4];
      #pragma unroll
      for (int i = 0; i < 4; ++i)
        #pragma unroll
        for (int jj = 0; jj < 4; ++jj)
          acc[i][jj] += a[i] * bq[jj];
    }
    __syncthreads();
  }

  #pragma unroll
  for (int i = 0; i < 4; ++i) {
    int m = m0 + ty * 4 + i;
    if (m >= M) continue;
    #pragma unroll
    for (int jj = 0; jj < 4; ++jj) {
      int n = n0 + tx * 4 + jj;
      if (n >= N) continue;
      float v = acc[i][jj] + bias[n];
      if (MODE == 2) v = fmaxf(v, 0.f);
      Cdst[(size_t)m * N + n] = v;
    }
  }
}

// ---------------- fp32 -> bf16 hi/lo split (4 elems/thread) ----------------
__global__ __launch_bounds__(WGS)
void cvt_split(const float* __restrict__ x, unsigned short* __restrict__ hi,
               unsigned short* __restrict__ lo, int n4)
{
  int i = blockIdx.x * WGS + threadIdx.x;
  if (i >= n4) return;
  f32x4 v = *(const f32x4*)(x + (size_t)i * 4);
  u16x4 h, l;
  #pragma unroll
  for (int d = 0; d < 4; ++d) {
    unsigned short hb = f2bf(v[d]);
    h[d] = hb;
    l[d] = f2bf(v[d] - bf2f(hb));
  }
  *(u16x4*)(hi + (size_t)i * 4) = h;
  *(u16x4*)(lo + (size_t)i * 4) = l;
}

// ---------------- MFMA bf16x3 vocab projection ----------------
// out[b][td][n] = sum_k OUT1[m][k] * W2[n][k] + b2[n],  m = td*32+b
// 3-term split: hi*hi + hi*lo + lo*hi (rel err ~2^-17).
// WG = 4 waves; tile 64(m) x 128(n); wave w owns n-sub w*32. Frags from global.
// mfma_f32_16x16x32_bf16: A-frag lane l = A[m0+(l&15)][k0+(l>>4)*8+j] (16B
// contiguous); B-frag same with n-row (B^T input); C: col=lane&15 (n),
// row=(lane>>4)*4+reg (m) [HW-verified mapping].
__global__ __launch_bounds__(WGS)
void gemm_mfma_out(const unsigned short* __restrict__ Ahi,
                   const unsigned short* __restrict__ Alo,
                   const unsigned short* __restrict__ Bhi,
                   const unsigned short* __restrict__ Blo,
                   const float* __restrict__ bias,
                   float* __restrict__ out)
{
  const int t = threadIdx.x;
  const int wv = t >> 6, lane = t & 63;
  const int r = lane & 15, q = lane >> 4;
  const int m0 = blockIdx.x * 64;              // m fastest: same-n blocks share W2 in L2
  const int n0 = blockIdx.y * 128 + wv * 32;
  const int M = TD_ * B_, N = VS_, K = H_;

  size_t aoff[4];
  #pragma unroll
  for (int fi = 0; fi < 4; ++fi) {
    int m = m0 + fi * 16 + r; if (m > M - 1) m = M - 1;
    aoff[fi] = (size_t)m * K;
  }
  size_t boff[2];
  #pragma unroll
  for (int nj = 0; nj < 2; ++nj) {
    int n = n0 + nj * 16 + r; if (n > N - 1) n = N - 1;
    boff[nj] = (size_t)n * K;
  }

  f32x4 acc[4][2];
  #pragma unroll
  for (int fi = 0; fi < 4; ++fi)
    #pragma unroll
    for (int nj = 0; nj < 2; ++nj) acc[fi][nj] = (f32x4){0.f, 0.f, 0.f, 0.f};

  for (int k0 = 0; k0 < K; k0 += 32) {
    const int ko = k0 + q * 8;
    s16x8 ah[4], al[4], bh[2], bl[2];
    #pragma unroll
    for (int fi = 0; fi < 4; ++fi) {
      ah[fi] = *(const s16x8*)(Ahi + aoff[fi] + ko);
      al[fi] = *(const s16x8*)(Alo + aoff[fi] + ko);
    }
    #pragma unroll
    for (int nj = 0; nj < 2; ++nj) {
      bh[nj] = *(const s16x8*)(Bhi + boff[nj] + ko);
      bl[nj] = *(const s16x8*)(Blo + boff[nj] + ko);
    }
    #pragma unroll
    for (int fi = 0; fi < 4; ++fi)
      #pragma unroll
      for (int nj = 0; nj < 2; ++nj) {
        acc[fi][nj] = __builtin_amdgcn_mfma_f32_16x16x32_bf16(ah[fi], bh[nj], acc[fi][nj], 0, 0, 0);
        acc[fi][nj] = __builtin_amdgcn_mfma_f32_16x16x32_bf16(ah[fi], bl[nj], acc[fi][nj], 0, 0, 0);
        acc[fi][nj] = __builtin_amdgcn_mfma_f32_16x16x32_bf16(al[fi], bh[nj], acc[fi][nj], 0, 0, 0);
      }
  }

  #pragma unroll
  for (int nj = 0; nj < 2; ++nj) {
    int n = n0 + nj * 16 + r;
    if (n >= N) continue;
    float bv = bias[n];
    #pragma unroll
    for (int fi = 0; fi < 4; ++fi) {
      #pragma unroll
      for (int e = 0; e < 4; ++e) {
        int m = m0 + fi * 16 + q * 4 + e;
        if (m < M) {
          int bidx = m & 31, td = m >> 5;
          out[((size_t)bidx * TD_ + td) * (size_t)N + n] = acc[fi][nj][e] + bv;
        }
      }
    }
  }
}

// ---------------- launch ----------------
extern "C" void kernel_launch(void* const* d_in, const int* in_sizes, int n_in,
                              void* d_out, int out_size, void* d_ws, size_t ws_size,
                              hipStream_t stream) {
  const int*   method_code    = (const int*)d_in[0];
  const int*   method_summary = (const int*)d_in[1];
  const float* enc_emb = (const float*)d_in[3];
  const float* enc_Wih = (const float*)d_in[4];
  const float* enc_Whh = (const float*)d_in[5];
  const float* enc_bih = (const float*)d_in[6];
  const float* enc_bhh = (const float*)d_in[7];
  const float* dec_emb = (const float*)d_in[8];
  const float* dec_Wih = (const float*)d_in[9];
  const float* dec_Whh = (const float*)d_in[10];
  const float* dec_bih = (const float*)d_in[11];
  const float* dec_bhh = (const float*)d_in[12];
  const float* W1 = (const float*)d_in[13];
  const float* b1 = (const float*)d_in[14];
  const float* W2 = (const float*)d_in[15];
  const float* b2 = (const float*)d_in[16];

  float* ws      = (float*)d_ws;
  float* enc_gx  = ws + OFF_ENC_GX;
  float* dec_gx  = ws + OFF_DEC_GX;
  float* enc_out = ws + OFF_ENC_OUT;
  float* hbuf    = ws + OFF_HBUF;
  float* Cmat    = ws + OFF_CMAT;
  float* OUT1    = ws + OFF_OUT1;
  unsigned short* W2hi = (unsigned short*)(ws + OFF_W2HI);
  unsigned short* W2lo = (unsigned short*)(ws + OFF_W2LO);
  unsigned short* O1hi = (unsigned short*)(ws + OFF_O1HI);
  unsigned short* O1lo = (unsigned short*)(ws + OFF_O1LO);

  // reset h exchange buffers (tags=0 == h_0 valid, payload zeros) every call
  hipMemsetAsync(hbuf, 0, SZ_HBUF * sizeof(float), stream);

  dim3 blk(WGS);
  // gx precompute (gather-GEMMs)
  gemm_bt<0><<<dim3(G3_ / 64, (S_ * B_) / 64), blk, 0, stream>>>(
      enc_emb, method_code, enc_Wih, enc_bih, enc_gx, S_ * B_, G3_, DE_);
  gemm_bt<1><<<dim3(G3_ / 64, (TD_ * B_ + 63) / 64), blk, 0, stream>>>(
      dec_emb, method_summary, dec_Wih, dec_bih, dec_gx, TD_ * B_, G3_, DE_);

  // persistent GRU chains: 256 WGs, barrier-free tagged-line exchange
  recurrence_kernel<<<NWGR, blk, 0, stream>>>(enc_gx, dec_gx,
                                              enc_Whh, enc_bhh, dec_Whh, dec_bhh,
                                              enc_out, hbuf, Cmat);

  // attention for all (td, b) in parallel
  attention_kernel<<<TD_ * B_, blk, 0, stream>>>(enc_out, Cmat);

  // fc1: OUT1 = relu(Cmat @ W1^T + b1)
  gemm_bt<2><<<dim3(H_ / 64, (TD_ * B_ + 63) / 64), blk, 0, stream>>>(
      Cmat, nullptr, W1, b1, OUT1, TD_ * B_, H_, 2 * H_);

  // bf16 hi/lo splits (W2 overlays now-dead enc_gx/dec_gx/enc_out regions)
  cvt_split<<<(VS_ * H_ / 4 + WGS - 1) / WGS, blk, 0, stream>>>(W2, W2hi, W2lo, VS_ * H_ / 4);
  cvt_split<<<(TD_ * B_ * H_ / 4 + WGS - 1) / WGS, blk, 0, stream>>>(OUT1, O1hi, O1lo, TD_ * B_ * H_ / 4);

  // vocab projection via 3-term bf16 MFMA
  gemm_mfma_out<<<dim3((TD_ * B_ + 63) / 64, (VS_ + 127) / 128), blk, 0, stream>>>(
      O1hi, O1lo, W2hi, W2lo, b2, (float*)d_out);
}

// Round 9
// 1561.470 us; speedup vs baseline: 1.1708x; 1.1708x over previous
//
#include <hip/hip_runtime.h>
#include <cmath>

#define WGS  256
#define NWGR 256         // recurrence workgroups (1 per CU)
#define DOMS 4           // independent batch domains (8 batches each)
#define JGN  64          // j-groups per domain (8 j each)
#define HBDW 5120        // dwords per parity buffer per domain (64 blocks x 80)

typedef float    f32x4 __attribute__((ext_vector_type(4)));
typedef unsigned u32x4 __attribute__((ext_vector_type(4)));
typedef short    s16x8 __attribute__((ext_vector_type(8)));
typedef unsigned short u16x4 __attribute__((ext_vector_type(4)));

// ---------------- sizes ----------------
#define B_   32
#define S_   200
#define L_   50
#define H_   512
#define DE_  256
#define VS_  30000
#define TD_  49          // L-1 decoder steps
#define G3_  1536        // 3*H

// ws layout (float offsets)
#define OFF_ENC_GX  ((size_t)0)                         // [200][32][1536]
#define SZ_ENC_GX   ((size_t)S_*B_*G3_)
#define OFF_DEC_GX  (OFF_ENC_GX + SZ_ENC_GX)            // [49][32][1536]
#define SZ_DEC_GX   ((size_t)TD_*B_*G3_)
#define OFF_ENC_OUT (OFF_DEC_GX + SZ_DEC_GX)            // [32][200][512]
#define SZ_ENC_OUT  ((size_t)B_*S_*H_)
#define OFF_HBUF    (OFF_ENC_OUT + SZ_ENC_OUT)          // [dom4][buf2][5120] tagged
#define SZ_HBUF     ((size_t)DOMS*2*HBDW)               // 40960 floats
#define OFF_CMAT    (OFF_HBUF + SZ_HBUF)                // [49][32][1024]
#define SZ_CMAT     ((size_t)TD_*B_*2*H_)
#define OFF_OUT1    (OFF_CMAT + SZ_CMAT)                // (dead fp32 slot, kept for layout)
#define SZ_OUT1     ((size_t)TD_*B_*H_)
// bf16 split overlays: W2hi/W2lo overlay enc_gx/dec_gx/enc_out (dead after
// attention): 15.36M floats < 15.55M (OFF_CMAT). O1 splits live past OUT1.
#define OFF_W2HI    ((size_t)0)                         // ushort[VS_*H_]
#define OFF_W2LO    ((size_t)(VS_*H_/2))
#define OFF_O1HI    (OFF_OUT1 + SZ_OUT1)                // ushort[TD_*B_*H_]
#define OFF_O1LO    (OFF_O1HI + (size_t)(TD_*B_*H_/2))

// LDS geometry for recurrence: k-blocks of 64 floats @ stride 68
#define RSTR 548
#define KBLK 68

__device__ __forceinline__ u32x4 load_u4_cc(const unsigned* p) {
  u32x4 v;
  asm volatile("global_load_dwordx4 %0, %1, off sc0 sc1" : "=v"(v) : "v"(p) : "memory");
  return v;
}

__device__ __forceinline__ float dot4(f32x4 a, f32x4 b) {
  return a.x * b.x + a.y * b.y + a.z * b.z + a.w * b.w;
}

// bf16 round-to-nearest-even
__device__ __forceinline__ unsigned short f2bf(float f) {
  unsigned u = __float_as_uint(f);
  return (unsigned short)((u + 0x7fffu + ((u >> 16) & 1u)) >> 16);
}
__device__ __forceinline__ float bf2f(unsigned short h) {
  return __uint_as_float(((unsigned)h) << 16);
}

// ---------------- persistent GRU-chain kernel, barrier-free (unchanged) ----------------
__global__ __launch_bounds__(WGS)
void recurrence_kernel(const float* __restrict__ enc_gx,
                       const float* __restrict__ dec_gx,
                       const float* __restrict__ eWhh, const float* __restrict__ eBhh,
                       const float* __restrict__ dWhh, const float* __restrict__ dBhh,
                       float* __restrict__ enc_out,
                       float* __restrict__ hbuf,
                       float* __restrict__ Cmat)
{
  __shared__ float hlds[8 * RSTR];
  __shared__ float red[768];

  const int t   = threadIdx.x;
  const int w   = blockIdx.x;
  const int dom = w >> 6;
  const int jg  = w & (JGN - 1);
  const int jl  = t & 7;
  const int kh  = t >> 3;
  const int bt_ = t >> 3;
  const int j   = (jg << 3) + jl;
  const int b_g = (dom << 3) + bt_;

  float* hdom = hbuf + (size_t)dom * (2 * HBDW);

  int rr[5], kb[5];
  #pragma unroll
  for (int i = 0; i < 5; ++i) {
    int g = i * 1024 + (t << 2);
    int blk = g / 80;
    rr[i] = g - blk * 80;
    kb[i] = blk << 3;
  }

  f32x4 wreg[3][4];
  auto load_w = [&](const float* __restrict__ W) {
    #pragma unroll
    for (int g = 0; g < 3; ++g)
      #pragma unroll
      for (int c = 0; c < 4; ++c)
        wreg[g][c] = *(const f32x4*)(W + (size_t)(g * H_ + j) * H_ + (kh << 4) + (c << 2));
  };
  load_w(eWhh);

  float bias_r = 0.f, bias_z = 0.f, bias_n = 0.f;
  if (t < 64) { bias_r = eBhh[j]; bias_z = eBhh[H_ + j]; bias_n = eBhh[2 * H_ + j]; }

  for (int s = 0; s < S_ + TD_; ++s) {
    const bool enc = (s < S_);
    __syncthreads();
    if (s == S_) {
      load_w(dWhh);
      if (t < 64) { bias_r = dBhh[j]; bias_z = dBhh[H_ + j]; bias_n = dBhh[2 * H_ + j]; }
    }

    float gxr = 0.f, gxz = 0.f, gxn = 0.f;
    if (t < 64) {
      const float* gx = enc ? (enc_gx + ((size_t)s * B_ + b_g) * G3_)
                            : (dec_gx + ((size_t)(s - S_) * B_ + b_g) * G3_);
      gxr = gx[j]; gxz = gx[H_ + j]; gxn = gx[2 * H_ + j];
    }

    {
      const unsigned* hb = (const unsigned*)(hdom + (size_t)(s & 1) * HBDW);
      const unsigned tagreq = (unsigned)s;
      u32x4 v0, v1, v2, v3, v4;
      while (true) {
        v0 = load_u4_cc(hb + 0 * 1024 + (t << 2));
        v1 = load_u4_cc(hb + 1 * 1024 + (t << 2));
        v2 = load_u4_cc(hb + 2 * 1024 + (t << 2));
        v3 = load_u4_cc(hb + 3 * 1024 + (t << 2));
        v4 = load_u4_cc(hb + 4 * 1024 + (t << 2));
        asm volatile("s_waitcnt vmcnt(0)" ::: "memory");
        bool ok = true;
        if ((rr[0] & 15) == 0) ok &= ((unsigned)v0.x >= tagreq);
        if ((rr[1] & 15) == 0) ok &= ((unsigned)v1.x >= tagreq);
        if ((rr[2] & 15) == 0) ok &= ((unsigned)v2.x >= tagreq);
        if ((rr[3] & 15) == 0) ok &= ((unsigned)v3.x >= tagreq);
        if ((rr[4] & 15) == 0) ok &= ((unsigned)v4.x >= tagreq);
        if (__all(ok)) break;
        __builtin_amdgcn_s_sleep(1);
      }
      #define SCAT(vv, ii) { \
        _Pragma("unroll") \
        for (int d = 0; d < 4; ++d) { \
          int pos = rr[ii] + d; \
          if ((pos & 15) != 0) { \
            int p = pos - 1 - (pos >> 4); \
            if (p < 64) { \
              int bb = p >> 3, k = kb[ii] + (p & 7); \
              hlds[bb * RSTR + ((k >> 6) * KBLK) + (k & 63)] = __uint_as_float(vv[d]); \
            } } } }
      SCAT(v0, 0) SCAT(v1, 1) SCAT(v2, 2) SCAT(v3, 3) SCAT(v4, 4)
      #undef SCAT
    }
    __syncthreads();

    float acc[3][8];
    #pragma unroll
    for (int g = 0; g < 3; ++g)
      #pragma unroll
      for (int b = 0; b < 8; ++b) acc[g][b] = 0.f;

    const int hoff = (kh >> 2) * KBLK + ((kh & 3) << 4);
    #pragma unroll
    for (int b = 0; b < 8; ++b) {
      const float* hp = &hlds[b * RSTR + hoff];
      f32x4 h0 = *(const f32x4*)(hp);
      f32x4 h1 = *(const f32x4*)(hp + 4);
      f32x4 h2 = *(const f32x4*)(hp + 8);
      f32x4 h3 = *(const f32x4*)(hp + 12);
      #pragma unroll
      for (int g = 0; g < 3; ++g)
        acc[g][b] += dot4(wreg[g][0], h0) + dot4(wreg[g][1], h1)
                   + dot4(wreg[g][2], h2) + dot4(wreg[g][3], h3);
    }

    #pragma unroll
    for (int g = 0; g < 3; ++g)
      #pragma unroll
      for (int b = 0; b < 8; ++b) {
        float v = acc[g][b];
        v += __shfl_xor(v, 8);
        v += __shfl_xor(v, 16);
        v += __shfl_xor(v, 32);
        acc[g][b] = v;
      }
    if ((t & 56) == 0) {
      const int base = ((t >> 6) * 8 + jl) * 24;
      #pragma unroll
      for (int g = 0; g < 3; ++g)
        #pragma unroll
        for (int b = 0; b < 8; ++b)
          red[base + g * 8 + b] = acc[g][b];
    }
    __syncthreads();

    if (t < 64) {
      float ar = 0.f, az = 0.f, an = 0.f;
      #pragma unroll
      for (int ww = 0; ww < 4; ++ww) {
        const int base = (ww * 8 + jl) * 24;
        ar += red[base + bt_];
        az += red[base + 8 + bt_];
        an += red[base + 16 + bt_];
      }
      float rg = 1.f / (1.f + expf(-(gxr + ar + bias_r)));
      float zg = 1.f / (1.f + expf(-(gxz + az + bias_z)));
      float ng = tanhf(gxn + rg * (an + bias_n));
      float hprev = hlds[bt_ * RSTR + ((j >> 6) * KBLK) + (j & 63)];
      float hn = (1.f - zg) * ng + zg * hprev;
      if (enc) enc_out[((size_t)b_g * S_ + s) * H_ + j] = hn;
      else     Cmat[((size_t)(s - S_) * B_ + b_g) * (2 * H_) + H_ + j] = hn;

      unsigned* pb = (unsigned*)(hdom + (size_t)((s + 1) & 1) * HBDW) + jg * 80;
      const unsigned tagv = (unsigned)(s + 1);
      float vA = __shfl(hn, (t - 1 - (t >> 4)) & 63);
      unsigned valA = ((t & 15) == 0) ? tagv : __float_as_uint(vA);
      __hip_atomic_store(pb + t, valA, __ATOMIC_RELAXED, __HIP_MEMORY_SCOPE_AGENT);
      float vB = __shfl(hn, (59 + t) & 63);
      if (t < 16) {
        unsigned valB = (t == 0) ? tagv : __float_as_uint(vB);
        __hip_atomic_store(pb + 64 + t, valB, __ATOMIC_RELAXED, __HIP_MEMORY_SCOPE_AGENT);
      }
    }
  }
}

// ---------------- attention kernel: one WG per (td, b) (unchanged) ----------------
__global__ __launch_bounds__(WGS)
void attention_kernel(const float* __restrict__ enc_out,
                      float* __restrict__ Cmat)
{
  const int task = blockIdx.x;
  const int td = task >> 5, b = task & 31;
  const int t = threadIdx.x;
  const float* h = Cmat + ((size_t)td * B_ + b) * (2 * H_) + H_;

  __shared__ float red[WGS];
  __shared__ float p[WGS];

  float sv = -1e30f;
  if (t < S_) {
    const float* eo = enc_out + ((size_t)b * S_ + t) * H_;
    float acc = 0.f;
    #pragma unroll 4
    for (int k = 0; k < H_; k += 4) {
      float4 e = *(const float4*)(eo + k);
      float4 hv = *(const float4*)(h + k);
      acc += e.x * hv.x + e.y * hv.y + e.z * hv.z + e.w * hv.w;
    }
    sv = acc;
  }
  red[t] = sv; __syncthreads();
  for (int o = 128; o; o >>= 1) { if (t < o) red[t] = fmaxf(red[t], red[t + o]); __syncthreads(); }
  float mx = red[0]; __syncthreads();
  float ev = (t < S_) ? expf(sv - mx) : 0.f;
  red[t] = ev; __syncthreads();
  for (int o = 128; o; o >>= 1) { if (t < o) red[t] += red[t + o]; __syncthreads(); }
  float inv = 1.f / red[0];
  p[t] = ev * inv;
  __syncthreads();

  const float* eo = enc_out + (size_t)b * S_ * H_ + (t << 1);
  float ax = 0.f, ay = 0.f;
  for (int i = 0; i < S_; ++i) {
    float pi = p[i];
    float2 v = *(const float2*)(eo + (size_t)i * H_);
    ax += pi * v.x; ay += pi * v.y;
  }
  float* cd = Cmat + ((size_t)td * B_ + b) * (2 * H_) + (t << 1);
  cd[0] = ax; cd[1] = ay;
}

// ---------------- 128x128 fp32 GEMM, 8x8 acc, gather/split epilogues ----------------
// MODE 0: A=enc_emb gathered (method_code),  out enc_gx,  M=6400,N=1536,K=256
// MODE 1: A=dec_emb gathered (method_summary), out dec_gx, M=1568,N=1536,K=256
// MODE 2: A=Cmat, relu, write O1hi/O1lo (bf16 split),      M=1568,N=512, K=1024
template<int MODE>
__launch_bounds__(WGS)
__global__ void gemm128g(const float* __restrict__ A,
                         const int* __restrict__ idx,
                         const float* __restrict__ Bw,
                         const float* __restrict__ bias,
                         float* __restrict__ Cdst,
                         unsigned short* __restrict__ Ohi,
                         unsigned short* __restrict__ Olo,
                         int M, int N, int K)
{
  const int APAD = 132;
  __shared__ float As[16 * APAD];
  __shared__ float Bs[16 * APAD];
  __shared__ int toks[128];
  const int n0 = blockIdx.x * 128, m0 = blockIdx.y * 128;
  const int t = threadIdx.x;
  const int tx = t & 15, ty = t >> 4;

  if (MODE <= 1) {
    if (t < 128) {
      int m = m0 + t;
      int tok = 0;
      if (m < M) {
        int bidx = m & 31, sr = m >> 5;
        tok = (MODE == 0) ? idx[bidx * S_ + sr] : idx[bidx * L_ + sr];
      }
      toks[t] = tok;
    }
    __syncthreads();
  }

  float acc[8][8];
  #pragma unroll
  for (int i = 0; i < 8; ++i)
    #pragma unroll
    for (int jj = 0; jj < 8; ++jj) acc[i][jj] = 0.f;

  const int srow = t >> 2, skk = (t & 3) * 4;
  for (int k0 = 0; k0 < K; k0 += 16) {
    #pragma unroll
    for (int u = 0; u < 2; ++u) {
      int row = srow + u * 64;
      const float* asrc;
      if (MODE <= 1) {
        asrc = A + (size_t)toks[row] * K + k0 + skk;
      } else {
        int m = m0 + row; if (m >= M) m = M - 1;
        asrc = A + (size_t)m * K + k0 + skk;
      }
      f32x4 av = *(const f32x4*)asrc;
      As[(skk + 0) * APAD + row] = av.x;
      As[(skk + 1) * APAD + row] = av.y;
      As[(skk + 2) * APAD + row] = av.z;
      As[(skk + 3) * APAD + row] = av.w;
      int n = n0 + row;                       // no n-edge in any mode
      f32x4 bv = *(const f32x4*)(Bw + (size_t)n * K + k0 + skk);
      Bs[(skk + 0) * APAD + row] = bv.x;
      Bs[(skk + 1) * APAD + row] = bv.y;
      Bs[(skk + 2) * APAD + row] = bv.z;
      Bs[(skk + 3) * APAD + row] = bv.w;
    }
    __syncthreads();
    #pragma unroll
    for (int k = 0; k < 16; ++k) {
      f32x4 a0 = *(const f32x4*)&As[k * APAD + ty * 8];
      f32x4 a1 = *(const f32x4*)&As[k * APAD + ty * 8 + 4];
      f32x4 b0 = *(const f32x4*)&Bs[k * APAD + tx * 4];
      f32x4 b1 = *(const f32x4*)&Bs[k * APAD + 64 + tx * 4];
      float a[8] = {a0.x, a0.y, a0.z, a0.w, a1.x, a1.y, a1.z, a1.w};
      float bb[8] = {b0.x, b0.y, b0.z, b0.w, b1.x, b1.y, b1.z, b1.w};
      #pragma unroll
      for (int i = 0; i < 8; ++i)
        #pragma unroll
        for (int jj = 0; jj < 8; ++jj)
          acc[i][jj] += a[i] * bb[jj];
    }
    __syncthreads();
  }

  if (MODE <= 1) {
    f32x4 bias0 = *(const f32x4*)(bias + n0 + tx * 4);
    f32x4 bias1 = *(const f32x4*)(bias + n0 + 64 + tx * 4);
    #pragma unroll
    for (int i = 0; i < 8; ++i) {
      int m = m0 + ty * 8 + i;
      if (m >= M) continue;
      float* orow = Cdst + (size_t)m * N;
      f32x4 v0 = { acc[i][0] + bias0.x, acc[i][1] + bias0.y,
                   acc[i][2] + bias0.z, acc[i][3] + bias0.w };
      f32x4 v1 = { acc[i][4] + bias1.x, acc[i][5] + bias1.y,
                   acc[i][6] + bias1.z, acc[i][7] + bias1.w };
      *(f32x4*)(orow + n0 + tx * 4) = v0;
      *(f32x4*)(orow + n0 + 64 + tx * 4) = v1;
    }
  } else {
    #pragma unroll
    for (int i = 0; i < 8; ++i) {
      int m = m0 + ty * 8 + i;
      if (m >= M) continue;
      #pragma unroll
      for (int half = 0; half < 2; ++half) {
        u16x4 hv, lv;
        #pragma unroll
        for (int d = 0; d < 4; ++d) {
          int n = n0 + half * 64 + tx * 4 + d;
          float v = fmaxf(acc[i][half * 4 + d] + bias[n], 0.f);
          unsigned short hb = f2bf(v);
          hv[d] = hb;
          lv[d] = f2bf(v - bf2f(hb));
        }
        size_t o = (size_t)m * H_ + n0 + half * 64 + tx * 4;
        *(u16x4*)(Ohi + o) = hv;
        *(u16x4*)(Olo + o) = lv;
      }
    }
  }
}

// ---------------- fp32 -> bf16 hi/lo split (W2) ----------------
__global__ __launch_bounds__(WGS)
void cvt_split(const float* __restrict__ x, unsigned short* __restrict__ hi,
               unsigned short* __restrict__ lo, int n4)
{
  int i = blockIdx.x * WGS + threadIdx.x;
  if (i >= n4) return;
  f32x4 v = *(const f32x4*)(x + (size_t)i * 4);
  u16x4 h, l;
  #pragma unroll
  for (int d = 0; d < 4; ++d) {
    unsigned short hb = f2bf(v[d]);
    h[d] = hb;
    l[d] = f2bf(v[d] - bf2f(hb));
  }
  *(u16x4*)(hi + (size_t)i * 4) = h;
  *(u16x4*)(lo + (size_t)i * 4) = l;
}

// ---------------- MFMA bf16x3 vocab projection, LDS-tiled ----------------
// C[m][n] = sum_k A[m][k]*B[n][k], 3-term hi/lo split. Tile 128x128, BK=32.
// 4 waves, each owns a 64x64 quadrant (4 m-frags x 4 n-frags, 48 MFMA/K-step).
// Reg-staged double-buffered LDS; XOR swizzle slot = c ^ ((row>>1)&3) applied
// identically on ds_write and ds_read (2-way conflicts = free).
__global__ __launch_bounds__(WGS)
void gemm_mfma_out(const unsigned short* __restrict__ Ahi,
                   const unsigned short* __restrict__ Alo,
                   const unsigned short* __restrict__ Bhi,
                   const unsigned short* __restrict__ Blo,
                   const float* __restrict__ bias,
                   float* __restrict__ out)
{
  __shared__ char smem[65536];   // 2 buffers x (Ahi|Alo|Bhi|Blo) x 8KB
  const int t = threadIdx.x;
  const int l = t & 63;
  const int wv = t >> 6;
  const int r = l & 15, q = l >> 4;
  const int m0 = blockIdx.x * 128;             // m fastest: same-n blocks share B in L2
  const int n0 = blockIdx.y * 128;
  const int M = TD_ * B_, N = VS_, K = H_;
  const int wm = (wv >> 1) << 6;
  const int wn = (wv & 1) << 6;

  // staging: 2 chunks per tile per thread; chunk -> (row, c); swizzled LDS slot
  int swoff[2];
  size_t aoff[2], boff[2];
  #pragma unroll
  for (int qq = 0; qq < 2; ++qq) {
    int chunk = qq * 256 + t;
    int row = chunk >> 2, c = chunk & 3;
    swoff[qq] = row * 64 + ((c ^ ((row >> 1) & 3)) << 4);
    int gm = m0 + row; if (gm >= M) gm = M - 1;
    aoff[qq] = (size_t)gm * K + c * 8;
    int gn = n0 + row; if (gn >= N) gn = N - 1;
    boff[qq] = (size_t)gn * K + c * 8;
  }

  u32x4 rg[8];
  auto gload = [&](int k0) {
    #pragma unroll
    for (int qq = 0; qq < 2; ++qq) {
      rg[qq]     = *(const u32x4*)(Ahi + aoff[qq] + k0);
      rg[2 + qq] = *(const u32x4*)(Alo + aoff[qq] + k0);
      rg[4 + qq] = *(const u32x4*)(Bhi + boff[qq] + k0);
      rg[6 + qq] = *(const u32x4*)(Blo + boff[qq] + k0);
    }
  };
  auto swrite = [&](char* buf) {
    #pragma unroll
    for (int qq = 0; qq < 2; ++qq) {
      *(u32x4*)(buf +         swoff[qq]) = rg[qq];
      *(u32x4*)(buf +  8192 + swoff[qq]) = rg[2 + qq];
      *(u32x4*)(buf + 16384 + swoff[qq]) = rg[4 + qq];
      *(u32x4*)(buf + 24576 + swoff[qq]) = rg[6 + qq];
    }
  };

  // fragment read offsets (swizzled)
  int afo[4], bfo[4];
  #pragma unroll
  for (int fi = 0; fi < 4; ++fi) {
    int ra = wm + fi * 16 + r;
    afo[fi] = ra * 64 + ((q ^ ((ra >> 1) & 3)) << 4);
    int rb = wn + fi * 16 + r;
    bfo[fi] = rb * 64 + ((q ^ ((rb >> 1) & 3)) << 4);
  }

  f32x4 acc[4][4];
  #pragma unroll
  for (int fi = 0; fi < 4; ++fi)
    #pragma unroll
    for (int nj = 0; nj < 4; ++nj) acc[fi][nj] = (f32x4){0.f, 0.f, 0.f, 0.f};

  gload(0);
  swrite(smem);
  __syncthreads();
  int cur = 0;
  const int NS = K / 32;   // 16
  for (int s = 0; s < NS; ++s) {
    if (s + 1 < NS) gload((s + 1) * 32);       // async, hides under compute
    char* buf = smem + cur * 32768;
    s16x8 ah[4], al[4], bh[4], bl[4];
    #pragma unroll
    for (int fi = 0; fi < 4; ++fi) {
      ah[fi] = *(const s16x8*)(buf +         afo[fi]);
      al[fi] = *(const s16x8*)(buf +  8192 + afo[fi]);
      bh[fi] = *(const s16x8*)(buf + 16384 + bfo[fi]);
      bl[fi] = *(const s16x8*)(buf + 24576 + bfo[fi]);
    }
    #pragma unroll
    for (int fi = 0; fi < 4; ++fi)
      #pragma unroll
      for (int nj = 0; nj < 4; ++nj) {
        acc[fi][nj] = __builtin_amdgcn_mfma_f32_16x16x32_bf16(ah[fi], bh[nj], acc[fi][nj], 0, 0, 0);
        acc[fi][nj] = __builtin_amdgcn_mfma_f32_16x16x32_bf16(ah[fi], bl[nj], acc[fi][nj], 0, 0, 0);
        acc[fi][nj] = __builtin_amdgcn_mfma_f32_16x16x32_bf16(al[fi], bh[nj], acc[fi][nj], 0, 0, 0);
      }
    if (s + 1 < NS) swrite(smem + (cur ^ 1) * 32768);   // vmcnt waits inserted by compiler
    __syncthreads();
    cur ^= 1;
  }

  // epilogue: C col = lane&15 (n-side/B), row = (lane>>4)*4+e (m-side/A)
  #pragma unroll
  for (int nj = 0; nj < 4; ++nj) {
    int n = n0 + wn + nj * 16 + r;
    if (n >= N) continue;
    float bv = bias[n];
    #pragma unroll
    for (int fi = 0; fi < 4; ++fi) {
      #pragma unroll
      for (int e = 0; e < 4; ++e) {
        int m = m0 + wm + fi * 16 + q * 4 + e;
        if (m < M) {
          int bidx = m & 31, td = m >> 5;
          out[((size_t)bidx * TD_ + td) * (size_t)N + n] = acc[fi][nj][e] + bv;
        }
      }
    }
  }
}

// ---------------- launch ----------------
extern "C" void kernel_launch(void* const* d_in, const int* in_sizes, int n_in,
                              void* d_out, int out_size, void* d_ws, size_t ws_size,
                              hipStream_t stream) {
  const int*   method_code    = (const int*)d_in[0];
  const int*   method_summary = (const int*)d_in[1];
  const float* enc_emb = (const float*)d_in[3];
  const float* enc_Wih = (const float*)d_in[4];
  const float* enc_Whh = (const float*)d_in[5];
  const float* enc_bih = (const float*)d_in[6];
  const float* enc_bhh = (const float*)d_in[7];
  const float* dec_emb = (const float*)d_in[8];
  const float* dec_Wih = (const float*)d_in[9];
  const float* dec_Whh = (const float*)d_in[10];
  const float* dec_bih = (const float*)d_in[11];
  const float* dec_bhh = (const float*)d_in[12];
  const float* W1 = (const float*)d_in[13];
  const float* b1 = (const float*)d_in[14];
  const float* W2 = (const float*)d_in[15];
  const float* b2 = (const float*)d_in[16];

  float* ws      = (float*)d_ws;
  float* enc_gx  = ws + OFF_ENC_GX;
  float* dec_gx  = ws + OFF_DEC_GX;
  float* enc_out = ws + OFF_ENC_OUT;
  float* hbuf    = ws + OFF_HBUF;
  float* Cmat    = ws + OFF_CMAT;
  unsigned short* W2hi = (unsigned short*)(ws + OFF_W2HI);
  unsigned short* W2lo = (unsigned short*)(ws + OFF_W2LO);
  unsigned short* O1hi = (unsigned short*)(ws + OFF_O1HI);
  unsigned short* O1lo = (unsigned short*)(ws + OFF_O1LO);

  // reset h exchange buffers (tags=0 == h_0 valid, payload zeros) every call
  hipMemsetAsync(hbuf, 0, SZ_HBUF * sizeof(float), stream);

  dim3 blk(WGS);
  // gx precompute (gather-GEMMs, 128x128 tiles)
  gemm128g<0><<<dim3(G3_ / 128, (S_ * B_) / 128), blk, 0, stream>>>(
      enc_emb, method_code, enc_Wih, enc_bih, enc_gx, nullptr, nullptr,
      S_ * B_, G3_, DE_);
  gemm128g<1><<<dim3(G3_ / 128, (TD_ * B_ + 127) / 128), blk, 0, stream>>>(
      dec_emb, method_summary, dec_Wih, dec_bih, dec_gx, nullptr, nullptr,
      TD_ * B_, G3_, DE_);

  // persistent GRU chains: 256 WGs, barrier-free tagged-line exchange
  recurrence_kernel<<<NWGR, blk, 0, stream>>>(enc_gx, dec_gx,
                                              enc_Whh, enc_bhh, dec_Whh, dec_bhh,
                                              enc_out, hbuf, Cmat);

  // attention for all (td, b) in parallel
  attention_kernel<<<TD_ * B_, blk, 0, stream>>>(enc_out, Cmat);

  // W2 bf16 split (overlays now-dead enc_gx/dec_gx/enc_out regions)
  cvt_split<<<(VS_ * H_ / 4 + WGS - 1) / WGS, blk, 0, stream>>>(
      W2, W2hi, W2lo, VS_ * H_ / 4);

  // fc1: relu(Cmat @ W1^T + b1) -> bf16 hi/lo directly
  gemm128g<2><<<dim3(H_ / 128, (TD_ * B_ + 127) / 128), blk, 0, stream>>>(
      Cmat, nullptr, W1, b1, nullptr, O1hi, O1lo, TD_ * B_, H_, 2 * H_);

  // vocab projection via 3-term bf16 MFMA, LDS-tiled
  gemm_mfma_out<<<dim3((TD_ * B_ + 127) / 128, (VS_ + 127) / 128), blk, 0, stream>>>(
      O1hi, O1lo, W2hi, W2lo, b2, (float*)d_out);
}

// Round 10
// 1496.702 us; speedup vs baseline: 1.2215x; 1.0433x over previous
//
#include <hip/hip_runtime.h>
#include <cmath>

#define WGS  256
#define NWGR 256         // recurrence workgroups (1 per CU)
#define DOMS 8           // independent batch domains (4 batches each)
#define JGN  32          // j-groups per domain (16 j each)
#define HBDW 2560        // dwords per parity buffer per domain (32 blocks x 80)

typedef float    f32x4 __attribute__((ext_vector_type(4)));
typedef unsigned u32x4 __attribute__((ext_vector_type(4)));
typedef short    s16x8 __attribute__((ext_vector_type(8)));
typedef unsigned short u16x4 __attribute__((ext_vector_type(4)));

// ---------------- sizes ----------------
#define B_   32
#define S_   200
#define L_   50
#define H_   512
#define DE_  256
#define VS_  30000
#define TD_  49          // L-1 decoder steps
#define G3_  1536        // 3*H

// ws layout (float offsets) — kept identical to round 9 (proven to fit):
// region [0, OFF_CMAT) is scratch for W2hi/W2lo (written AFTER attention);
// enc_out lives inside it and is dead by then. gx buffers no longer exist.
#define OFF_ENC_OUT ((size_t)(S_*B_*G3_) + (size_t)(TD_*B_*G3_))   // 12.24M
#define SZ_ENC_OUT  ((size_t)B_*S_*H_)
#define OFF_HBUF    (OFF_ENC_OUT + SZ_ENC_OUT)
#define SZ_HBUF     ((size_t)DOMS*2*HBDW)               // 40960 floats
#define OFF_CMAT    (OFF_HBUF + SZ_HBUF)
#define SZ_CMAT     ((size_t)TD_*B_*2*H_)
#define OFF_OUT1    (OFF_CMAT + SZ_CMAT)
#define SZ_OUT1     ((size_t)TD_*B_*H_)
#define OFF_W2HI    ((size_t)0)                         // ushort[VS_*H_]
#define OFF_W2LO    ((size_t)(VS_*H_/2))
#define OFF_O1HI    (OFF_OUT1 + SZ_OUT1)                // ushort[TD_*B_*H_]
#define OFF_O1LO    (OFF_O1HI + (size_t)(TD_*B_*H_/2))

// LDS geometry for recurrence: k-blocks of 64 floats @ stride 68
#define RSTR 548
#define KBLK 68

__device__ __forceinline__ u32x4 load_u4_cc(const unsigned* p) {
  u32x4 v;
  asm volatile("global_load_dwordx4 %0, %1, off sc0 sc1" : "=v"(v) : "v"(p) : "memory");
  return v;
}

__device__ __forceinline__ float dot4(f32x4 a, f32x4 b) {
  return a.x * b.x + a.y * b.y + a.z * b.z + a.w * b.w;
}

// bf16 round-to-nearest-even
__device__ __forceinline__ unsigned short f2bf(float f) {
  unsigned u = __float_as_uint(f);
  return (unsigned short)((u + 0x7fffu + ((u >> 16) & 1u)) >> 16);
}
__device__ __forceinline__ float bf2f(unsigned short h) {
  return __uint_as_float(((unsigned)h) << 16);
}

// ---------------- persistent GRU-chain kernel, barrier-free, gx fused ----------------
// 256 WGs: dom = w>>5 (4 batches), jg = w&31 (16 j-values).
// Compute thread: jl = t&15, kh = t>>4 (16 slices of 32 k for h; 16 k for x).
// Tail t<64: jl = t&15, bt = t>>4.
// Exchange block (per jg): 80 dwords = 5 lines; tag at pos%16==0; payload
// p = pos-1-pos/16 (p<64), p = b*16+jl. Published by exactly 2 wave-store
// instructions -> each 64B line written whole -> tag+payload atomic at L3.
__global__ __launch_bounds__(WGS)
void recurrence_kernel(const int* __restrict__ mc, const int* __restrict__ ms,
                       const float* __restrict__ enc_emb,
                       const float* __restrict__ eWih, const float* __restrict__ eBih,
                       const float* __restrict__ dec_emb,
                       const float* __restrict__ dWih, const float* __restrict__ dBih,
                       const float* __restrict__ eWhh, const float* __restrict__ eBhh,
                       const float* __restrict__ dWhh, const float* __restrict__ dBhh,
                       float* __restrict__ enc_out,
                       float* __restrict__ hbuf,
                       float* __restrict__ Cmat)
{
  __shared__ float hlds[4 * RSTR];    //  8768 B: 4 batches x 512 k
  __shared__ float xlds[4 * 256];     //  4096 B: 4 batches x 256 (x_emb)
  __shared__ float red[768];          //  h partials  [wave4][jl16][g3][b4]
  __shared__ float red2[768];         //  gx partials

  const int t   = threadIdx.x;
  const int w   = blockIdx.x;
  const int dom = w >> 5;
  const int jg  = w & (JGN - 1);
  const int kh  = t >> 4;             // 0..15
  const int j   = (jg << 4) + (t & 15);
  const int bt_ = t >> 4;             // tail batch (t<64): 0..3
  const int b_g = (dom << 2) + bt_;
  const int xb  = t >> 6, xc = t & 63;           // x staging role
  const int xb_g = (dom << 2) + xb;

  float* hdom = hbuf + (size_t)dom * (2 * HBDW);

  // poll/scatter constants: 3 chunks (chunk 2 only for t<128; 2560 dw total)
  int rr[3], kb[3];
  #pragma unroll
  for (int i = 0; i < 3; ++i) {
    int g = i * 1024 + (t << 2);
    int blk = g / 80;
    rr[i] = g - blk * 80;
    kb[i] = blk << 4;                 // k base of block (16 j per block)
  }

  // Whh in VGPRs: 3 gates x 32 k (per-thread slice at kh*32)
  f32x4 whh[3][8];
  auto load_whh = [&](const float* __restrict__ W) {
    #pragma unroll
    for (int g = 0; g < 3; ++g)
      #pragma unroll
      for (int c = 0; c < 8; ++c)
        whh[g][c] = *(const f32x4*)(W + (size_t)(g * H_ + j) * H_ + (kh << 5) + (c << 2));
  };
  // Wih in VGPRs: 3 gates x 16 k (per-thread slice at kh*16, K=256)
  f32x4 wih[3][4];
  auto load_wih = [&](const float* __restrict__ W) {
    #pragma unroll
    for (int g = 0; g < 3; ++g)
      #pragma unroll
      for (int c = 0; c < 4; ++c)
        wih[g][c] = *(const f32x4*)(W + (size_t)(g * H_ + j) * DE_ + (kh << 4) + (c << 2));
  };
  load_whh(eWhh);
  load_wih(eWih);

  float bhr = 0.f, bhz = 0.f, bhn = 0.f, bxr = 0.f, bxz = 0.f, bxn = 0.f;
  if (t < 64) {
    bhr = eBhh[j]; bhz = eBhh[H_ + j]; bhn = eBhh[2 * H_ + j];
    bxr = eBih[j]; bxz = eBih[H_ + j]; bxn = eBih[2 * H_ + j];
  }

  for (int s = 0; s < S_ + TD_; ++s) {
    const bool enc = (s < S_);
    __syncthreads();    // hlds/xlds/red from prev step fully consumed
    if (s == S_) {      // switch to decoder weights
      load_whh(dWhh);
      load_wih(dWih);
      if (t < 64) {
        bhr = dBhh[j]; bhz = dBhh[H_ + j]; bhn = dBhh[2 * H_ + j];
        bxr = dBih[j]; bxz = dBih[H_ + j]; bxn = dBih[2 * H_ + j];
      }
    }

    // ---- stage x_s (embedding gather): 1 f32x4 per thread ----
    {
      int tok = enc ? mc[xb_g * S_ + s] : ms[xb_g * L_ + (s - S_)];
      const float* emb = enc ? enc_emb : dec_emb;
      f32x4 xv = *(const f32x4*)(emb + (size_t)tok * DE_ + (xc << 2));
      *(f32x4*)&xlds[xb * 256 + (xc << 2)] = xv;
    }

    // ---- poll h_s: tagged lines until fresh, scatter to LDS ----
    {
      const unsigned* hb = (const unsigned*)(hdom + (size_t)(s & 1) * HBDW);
      const unsigned tagreq = (unsigned)s;
      u32x4 v0, v1, v2;
      while (true) {
        v0 = load_u4_cc(hb + 0 * 1024 + (t << 2));
        v1 = load_u4_cc(hb + 1 * 1024 + (t << 2));
        if (t < 128) v2 = load_u4_cc(hb + 2 * 1024 + (t << 2));
        asm volatile("s_waitcnt vmcnt(0)" ::: "memory");
        bool ok = true;
        if ((rr[0] & 15) == 0) ok &= ((unsigned)v0.x >= tagreq);
        if ((rr[1] & 15) == 0) ok &= ((unsigned)v1.x >= tagreq);
        if (t < 128 && (rr[2] & 15) == 0) ok &= ((unsigned)v2.x >= tagreq);
        if (__all(ok)) break;
        __builtin_amdgcn_s_sleep(1);
      }
      #define SCAT(vv, ii) { \
        _Pragma("unroll") \
        for (int d = 0; d < 4; ++d) { \
          int pos = rr[ii] + d; \
          if ((pos & 15) != 0) { \
            int p = pos - 1 - (pos >> 4); \
            if (p < 64) { \
              int bb = p >> 4, k = kb[ii] + (p & 15); \
              hlds[bb * RSTR + ((k >> 6) * KBLK) + (k & 63)] = __uint_as_float(vv[d]); \
            } } } }
      SCAT(v0, 0) SCAT(v1, 1)
      if (t < 128) { SCAT(v2, 2) }
      #undef SCAT
    }
    __syncthreads();

    // ---- compute: h-dots (32 k) + gx-dots (16 k) for 4 batches, 3 gates ----
    float acc[3][4], acx[3][4];
    #pragma unroll
    for (int g = 0; g < 3; ++g)
      #pragma unroll
      for (int b = 0; b < 4; ++b) { acc[g][b] = 0.f; acx[g][b] = 0.f; }

    const int hoff = (kh >> 1) * KBLK + (kh & 1) * 32;
    #pragma unroll
    for (int b = 0; b < 4; ++b) {
      const float* hp = &hlds[b * RSTR + hoff];
      #pragma unroll
      for (int c = 0; c < 8; ++c) {
        f32x4 hv = *(const f32x4*)(hp + (c << 2));
        acc[0][b] += dot4(whh[0][c], hv);
        acc[1][b] += dot4(whh[1][c], hv);
        acc[2][b] += dot4(whh[2][c], hv);
      }
      const float* xp = &xlds[b * 256 + (kh << 4)];
      #pragma unroll
      for (int c = 0; c < 4; ++c) {
        f32x4 xv = *(const f32x4*)(xp + (c << 2));
        acx[0][b] += dot4(wih[0][c], xv);
        acx[1][b] += dot4(wih[1][c], xv);
        acx[2][b] += dot4(wih[2][c], xv);
      }
    }

    // fold kh bits 0-1 (t bits 4-5) within wave
    #pragma unroll
    for (int g = 0; g < 3; ++g)
      #pragma unroll
      for (int b = 0; b < 4; ++b) {
        float v = acc[g][b];
        v += __shfl_xor(v, 16); v += __shfl_xor(v, 32);
        acc[g][b] = v;
        float u = acx[g][b];
        u += __shfl_xor(u, 16); u += __shfl_xor(u, 32);
        acx[g][b] = u;
      }
    if ((t & 48) == 0) {                 // 16 lanes per wave (one per jl)
      const int base = (t >> 6) * 192 + (t & 15) * 12;
      #pragma unroll
      for (int g = 0; g < 3; ++g)
        #pragma unroll
        for (int b = 0; b < 4; ++b) {
          red[base + g * 4 + b]  = acc[g][b];
          red2[base + g * 4 + b] = acx[g][b];
        }
    }
    __syncthreads();

    // ---- tail (t<64): combine 4 wave-partials, gate math, publish ----
    if (t < 64) {
      float ar = 0.f, az = 0.f, an = 0.f, xr = 0.f, xz = 0.f, xn = 0.f;
      #pragma unroll
      for (int ww = 0; ww < 4; ++ww) {
        const int base = ww * 192 + (t & 15) * 12 + bt_;
        ar += red[base];      az += red[base + 4];  an += red[base + 8];
        xr += red2[base];     xz += red2[base + 4]; xn += red2[base + 8];
      }
      float gxr = xr + bxr, gxz = xz + bxz, gxn = xn + bxn;
      float rg = 1.f / (1.f + expf(-(gxr + ar + bhr)));
      float zg = 1.f / (1.f + expf(-(gxz + az + bhz)));
      float ng = tanhf(gxn + rg * (an + bhn));
      float hprev = hlds[bt_ * RSTR + ((j >> 6) * KBLK) + (j & 63)];
      float hn = (1.f - zg) * ng + zg * hprev;
      if (enc) enc_out[((size_t)b_g * S_ + s) * H_ + j] = hn;
      else     Cmat[((size_t)(s - S_) * B_ + b_g) * (2 * H_) + H_ + j] = hn;

      // publish h_{s+1}: payload index p == tail thread index (b*16+jl == t)
      unsigned* pb = (unsigned*)(hdom + (size_t)((s + 1) & 1) * HBDW) + jg * 80;
      const unsigned tagv = (unsigned)(s + 1);
      float vA = __shfl(hn, (t - 1 - (t >> 4)) & 63);
      unsigned valA = ((t & 15) == 0) ? tagv : __float_as_uint(vA);
      __hip_atomic_store(pb + t, valA, __ATOMIC_RELAXED, __HIP_MEMORY_SCOPE_AGENT);
      float vB = __shfl(hn, (59 + t) & 63);
      if (t < 16) {
        unsigned valB = (t == 0) ? tagv : __float_as_uint(vB);
        __hip_atomic_store(pb + 64 + t, valB, __ATOMIC_RELAXED, __HIP_MEMORY_SCOPE_AGENT);
      }
    }
  }
}

// ---------------- attention kernel: one WG per (td, b) (unchanged) ----------------
__global__ __launch_bounds__(WGS)
void attention_kernel(const float* __restrict__ enc_out,
                      float* __restrict__ Cmat)
{
  const int task = blockIdx.x;
  const int td = task >> 5, b = task & 31;
  const int t = threadIdx.x;
  const float* h = Cmat + ((size_t)td * B_ + b) * (2 * H_) + H_;

  __shared__ float red[WGS];
  __shared__ float p[WGS];

  float sv = -1e30f;
  if (t < S_) {
    const float* eo = enc_out + ((size_t)b * S_ + t) * H_;
    float acc = 0.f;
    #pragma unroll 4
    for (int k = 0; k < H_; k += 4) {
      float4 e = *(const float4*)(eo + k);
      float4 hv = *(const float4*)(h + k);
      acc += e.x * hv.x + e.y * hv.y + e.z * hv.z + e.w * hv.w;
    }
    sv = acc;
  }
  red[t] = sv; __syncthreads();
  for (int o = 128; o; o >>= 1) { if (t < o) red[t] = fmaxf(red[t], red[t + o]); __syncthreads(); }
  float mx = red[0]; __syncthreads();
  float ev = (t < S_) ? expf(sv - mx) : 0.f;
  red[t] = ev; __syncthreads();
  for (int o = 128; o; o >>= 1) { if (t < o) red[t] += red[t + o]; __syncthreads(); }
  float inv = 1.f / red[0];
  p[t] = ev * inv;
  __syncthreads();

  const float* eo = enc_out + (size_t)b * S_ * H_ + (t << 1);
  float ax = 0.f, ay = 0.f;
  for (int i = 0; i < S_; ++i) {
    float pi = p[i];
    float2 v = *(const float2*)(eo + (size_t)i * H_);
    ax += pi * v.x; ay += pi * v.y;
  }
  float* cd = Cmat + ((size_t)td * B_ + b) * (2 * H_) + (t << 1);
  cd[0] = ax; cd[1] = ay;
}

// ---------------- 128x128 fp32 GEMM, 8x8 acc, relu+bf16-split epilogue ----------------
// fc1: A=Cmat, relu, write O1hi/O1lo,  M=1568, N=512, K=1024
__launch_bounds__(WGS)
__global__ void gemm128_fc1(const float* __restrict__ A,
                            const float* __restrict__ Bw,
                            const float* __restrict__ bias,
                            unsigned short* __restrict__ Ohi,
                            unsigned short* __restrict__ Olo,
                            int M, int N, int K)
{
  const int APAD = 132;
  __shared__ float As[16 * APAD];
  __shared__ float Bs[16 * APAD];
  const int n0 = blockIdx.x * 128, m0 = blockIdx.y * 128;
  const int t = threadIdx.x;
  const int tx = t & 15, ty = t >> 4;

  float acc[8][8];
  #pragma unroll
  for (int i = 0; i < 8; ++i)
    #pragma unroll
    for (int jj = 0; jj < 8; ++jj) acc[i][jj] = 0.f;

  const int srow = t >> 2, skk = (t & 3) * 4;
  for (int k0 = 0; k0 < K; k0 += 16) {
    #pragma unroll
    for (int u = 0; u < 2; ++u) {
      int row = srow + u * 64;
      int m = m0 + row; if (m >= M) m = M - 1;
      f32x4 av = *(const f32x4*)(A + (size_t)m * K + k0 + skk);
      As[(skk + 0) * APAD + row] = av.x;
      As[(skk + 1) * APAD + row] = av.y;
      As[(skk + 2) * APAD + row] = av.z;
      As[(skk + 3) * APAD + row] = av.w;
      int n = n0 + row;
      f32x4 bv = *(const f32x4*)(Bw + (size_t)n * K + k0 + skk);
      Bs[(skk + 0) * APAD + row] = bv.x;
      Bs[(skk + 1) * APAD + row] = bv.y;
      Bs[(skk + 2) * APAD + row] = bv.z;
      Bs[(skk + 3) * APAD + row] = bv.w;
    }
    __syncthreads();
    #pragma unroll
    for (int k = 0; k < 16; ++k) {
      f32x4 a0 = *(const f32x4*)&As[k * APAD + ty * 8];
      f32x4 a1 = *(const f32x4*)&As[k * APAD + ty * 8 + 4];
      f32x4 b0 = *(const f32x4*)&Bs[k * APAD + tx * 4];
      f32x4 b1 = *(const f32x4*)&Bs[k * APAD + 64 + tx * 4];
      float a[8] = {a0.x, a0.y, a0.z, a0.w, a1.x, a1.y, a1.z, a1.w};
      float bb[8] = {b0.x, b0.y, b0.z, b0.w, b1.x, b1.y, b1.z, b1.w};
      #pragma unroll
      for (int i = 0; i < 8; ++i)
        #pragma unroll
        for (int jj = 0; jj < 8; ++jj)
          acc[i][jj] += a[i] * bb[jj];
    }
    __syncthreads();
  }

  #pragma unroll
  for (int i = 0; i < 8; ++i) {
    int m = m0 + ty * 8 + i;
    if (m >= M) continue;
    #pragma unroll
    for (int half = 0; half < 2; ++half) {
      u16x4 hv, lv;
      #pragma unroll
      for (int d = 0; d < 4; ++d) {
        int n = n0 + half * 64 + tx * 4 + d;
        float v = fmaxf(acc[i][half * 4 + d] + bias[n], 0.f);
        unsigned short hb = f2bf(v);
        hv[d] = hb;
        lv[d] = f2bf(v - bf2f(hb));
      }
      size_t o = (size_t)m * H_ + n0 + half * 64 + tx * 4;
      *(u16x4*)(Ohi + o) = hv;
      *(u16x4*)(Olo + o) = lv;
    }
  }
}

// ---------------- fp32 -> bf16 hi/lo split (W2) ----------------
__global__ __launch_bounds__(WGS)
void cvt_split(const float* __restrict__ x, unsigned short* __restrict__ hi,
               unsigned short* __restrict__ lo, int n4)
{
  int i = blockIdx.x * WGS + threadIdx.x;
  if (i >= n4) return;
  f32x4 v = *(const f32x4*)(x + (size_t)i * 4);
  u16x4 h, l;
  #pragma unroll
  for (int d = 0; d < 4; ++d) {
    unsigned short hb = f2bf(v[d]);
    h[d] = hb;
    l[d] = f2bf(v[d] - bf2f(hb));
  }
  *(u16x4*)(hi + (size_t)i * 4) = h;
  *(u16x4*)(lo + (size_t)i * 4) = l;
}

// ---------------- MFMA bf16x3 vocab projection, LDS-tiled (unchanged) ----------------
__global__ __launch_bounds__(WGS)
void gemm_mfma_out(const unsigned short* __restrict__ Ahi,
                   const unsigned short* __restrict__ Alo,
                   const unsigned short* __restrict__ Bhi,
                   const unsigned short* __restrict__ Blo,
                   const float* __restrict__ bias,
                   float* __restrict__ out)
{
  __shared__ char smem[65536];   // 2 buffers x (Ahi|Alo|Bhi|Blo) x 8KB
  const int t = threadIdx.x;
  const int l = t & 63;
  const int wv = t >> 6;
  const int r = l & 15, q = l >> 4;
  const int m0 = blockIdx.x * 128;
  const int n0 = blockIdx.y * 128;
  const int M = TD_ * B_, N = VS_, K = H_;
  const int wm = (wv >> 1) << 6;
  const int wn = (wv & 1) << 6;

  int swoff[2];
  size_t aoff[2], boff[2];
  #pragma unroll
  for (int qq = 0; qq < 2; ++qq) {
    int chunk = qq * 256 + t;
    int row = chunk >> 2, c = chunk & 3;
    swoff[qq] = row * 64 + ((c ^ ((row >> 1) & 3)) << 4);
    int gm = m0 + row; if (gm >= M) gm = M - 1;
    aoff[qq] = (size_t)gm * K + c * 8;
    int gn = n0 + row; if (gn >= N) gn = N - 1;
    boff[qq] = (size_t)gn * K + c * 8;
  }

  u32x4 rg[8];
  auto gload = [&](int k0) {
    #pragma unroll
    for (int qq = 0; qq < 2; ++qq) {
      rg[qq]     = *(const u32x4*)(Ahi + aoff[qq] + k0);
      rg[2 + qq] = *(const u32x4*)(Alo + aoff[qq] + k0);
      rg[4 + qq] = *(const u32x4*)(Bhi + boff[qq] + k0);
      rg[6 + qq] = *(const u32x4*)(Blo + boff[qq] + k0);
    }
  };
  auto swrite = [&](char* buf) {
    #pragma unroll
    for (int qq = 0; qq < 2; ++qq) {
      *(u32x4*)(buf +         swoff[qq]) = rg[qq];
      *(u32x4*)(buf +  8192 + swoff[qq]) = rg[2 + qq];
      *(u32x4*)(buf + 16384 + swoff[qq]) = rg[4 + qq];
      *(u32x4*)(buf + 24576 + swoff[qq]) = rg[6 + qq];
    }
  };

  int afo[4], bfo[4];
  #pragma unroll
  for (int fi = 0; fi < 4; ++fi) {
    int ra = wm + fi * 16 + r;
    afo[fi] = ra * 64 + ((q ^ ((ra >> 1) & 3)) << 4);
    int rb = wn + fi * 16 + r;
    bfo[fi] = rb * 64 + ((q ^ ((rb >> 1) & 3)) << 4);
  }

  f32x4 acc[4][4];
  #pragma unroll
  for (int fi = 0; fi < 4; ++fi)
    #pragma unroll
    for (int nj = 0; nj < 4; ++nj) acc[fi][nj] = (f32x4){0.f, 0.f, 0.f, 0.f};

  gload(0);
  swrite(smem);
  __syncthreads();
  int cur = 0;
  const int NS = K / 32;   // 16
  for (int s = 0; s < NS; ++s) {
    if (s + 1 < NS) gload((s + 1) * 32);
    char* buf = smem + cur * 32768;
    s16x8 ah[4], al[4], bh[4], bl[4];
    #pragma unroll
    for (int fi = 0; fi < 4; ++fi) {
      ah[fi] = *(const s16x8*)(buf +         afo[fi]);
      al[fi] = *(const s16x8*)(buf +  8192 + afo[fi]);
      bh[fi] = *(const s16x8*)(buf + 16384 + bfo[fi]);
      bl[fi] = *(const s16x8*)(buf + 24576 + bfo[fi]);
    }
    #pragma unroll
    for (int fi = 0; fi < 4; ++fi)
      #pragma unroll
      for (int nj = 0; nj < 4; ++nj) {
        acc[fi][nj] = __builtin_amdgcn_mfma_f32_16x16x32_bf16(ah[fi], bh[nj], acc[fi][nj], 0, 0, 0);
        acc[fi][nj] = __builtin_amdgcn_mfma_f32_16x16x32_bf16(ah[fi], bl[nj], acc[fi][nj], 0, 0, 0);
        acc[fi][nj] = __builtin_amdgcn_mfma_f32_16x16x32_bf16(al[fi], bh[nj], acc[fi][nj], 0, 0, 0);
      }
    if (s + 1 < NS) swrite(smem + (cur ^ 1) * 32768);
    __syncthreads();
    cur ^= 1;
  }

  #pragma unroll
  for (int nj = 0; nj < 4; ++nj) {
    int n = n0 + wn + nj * 16 + r;
    if (n >= N) continue;
    float bv = bias[n];
    #pragma unroll
    for (int fi = 0; fi < 4; ++fi) {
      #pragma unroll
      for (int e = 0; e < 4; ++e) {
        int m = m0 + wm + fi * 16 + q * 4 + e;
        if (m < M) {
          int bidx = m & 31, td = m >> 5;
          out[((size_t)bidx * TD_ + td) * (size_t)N + n] = acc[fi][nj][e] + bv;
        }
      }
    }
  }
}

// ---------------- launch ----------------
extern "C" void kernel_launch(void* const* d_in, const int* in_sizes, int n_in,
                              void* d_out, int out_size, void* d_ws, size_t ws_size,
                              hipStream_t stream) {
  const int*   method_code    = (const int*)d_in[0];
  const int*   method_summary = (const int*)d_in[1];
  const float* enc_emb = (const float*)d_in[3];
  const float* enc_Wih = (const float*)d_in[4];
  const float* enc_Whh = (const float*)d_in[5];
  const float* enc_bih = (const float*)d_in[6];
  const float* enc_bhh = (const float*)d_in[7];
  const float* dec_emb = (const float*)d_in[8];
  const float* dec_Wih = (const float*)d_in[9];
  const float* dec_Whh = (const float*)d_in[10];
  const float* dec_bih = (const float*)d_in[11];
  const float* dec_bhh = (const float*)d_in[12];
  const float* W1 = (const float*)d_in[13];
  const float* b1 = (const float*)d_in[14];
  const float* W2 = (const float*)d_in[15];
  const float* b2 = (const float*)d_in[16];

  float* ws      = (float*)d_ws;
  float* enc_out = ws + OFF_ENC_OUT;
  float* hbuf    = ws + OFF_HBUF;
  float* Cmat    = ws + OFF_CMAT;
  unsigned short* W2hi = (unsigned short*)(ws + OFF_W2HI);
  unsigned short* W2lo = (unsigned short*)(ws + OFF_W2LO);
  unsigned short* O1hi = (unsigned short*)(ws + OFF_O1HI);
  unsigned short* O1lo = (unsigned short*)(ws + OFF_O1LO);

  // reset h exchange buffers (tags=0 == h_0 valid, payload zeros) every call
  hipMemsetAsync(hbuf, 0, SZ_HBUF * sizeof(float), stream);

  dim3 blk(WGS);

  // persistent GRU chains (gx fused): 256 WGs, 8 domains, tagged-line exchange
  recurrence_kernel<<<NWGR, blk, 0, stream>>>(
      method_code, method_summary,
      enc_emb, enc_Wih, enc_bih,
      dec_emb, dec_Wih, dec_bih,
      enc_Whh, enc_bhh, dec_Whh, dec_bhh,
      enc_out, hbuf, Cmat);

  // attention for all (td, b) in parallel
  attention_kernel<<<TD_ * B_, blk, 0, stream>>>(enc_out, Cmat);

  // W2 bf16 split (overlays now-dead enc_out region; runs after attention)
  cvt_split<<<(VS_ * H_ / 4 + WGS - 1) / WGS, blk, 0, stream>>>(
      W2, W2hi, W2lo, VS_ * H_ / 4);

  // fc1: relu(Cmat @ W1^T + b1) -> bf16 hi/lo directly
  gemm128_fc1<<<dim3(H_ / 128, (TD_ * B_ + 127) / 128), blk, 0, stream>>>(
      Cmat, W1, b1, O1hi, O1lo, TD_ * B_, H_, 2 * H_);

  // vocab projection via 3-term bf16 MFMA, LDS-tiled
  gemm_mfma_out<<<dim3((TD_ * B_ + 127) / 128, (VS_ + 127) / 128), blk, 0, stream>>>(
      O1hi, O1lo, W2hi, W2lo, b2, (float*)d_out);
}

// Round 11
// 1406.821 us; speedup vs baseline: 1.2995x; 1.0639x over previous
//
#include <hip/hip_runtime.h>
#include <cmath>

#define WGS  256
#define NWGR 256         // recurrence workgroups (1 per CU)
#define DOMS 8           // independent batch domains (4 batches each)
#define JGN  32          // j-groups per domain (16 j each)
#define HBDW 2560        // dwords per parity buffer per domain (32 blocks x 80)
#define TDG  4           // td per attention WG

typedef float    f32x4 __attribute__((ext_vector_type(4)));
typedef unsigned u32x4 __attribute__((ext_vector_type(4)));
typedef short    s16x8 __attribute__((ext_vector_type(8)));
typedef unsigned short u16x4 __attribute__((ext_vector_type(4)));

// ---------------- sizes ----------------
#define B_   32
#define S_   200
#define L_   50
#define H_   512
#define DE_  256
#define VS_  30000
#define TD_  49          // L-1 decoder steps
#define G3_  1536        // 3*H

// ws layout (float offsets) — same as round 10 (proven):
#define OFF_ENC_OUT ((size_t)(S_*B_*G3_) + (size_t)(TD_*B_*G3_))   // 12.24M
#define SZ_ENC_OUT  ((size_t)B_*S_*H_)
#define OFF_HBUF    (OFF_ENC_OUT + SZ_ENC_OUT)
#define SZ_HBUF     ((size_t)DOMS*2*HBDW)               // 40960 floats
#define OFF_CMAT    (OFF_HBUF + SZ_HBUF)
#define SZ_CMAT     ((size_t)TD_*B_*2*H_)
#define OFF_OUT1    (OFF_CMAT + SZ_CMAT)
#define SZ_OUT1     ((size_t)TD_*B_*H_)
#define OFF_W2HI    ((size_t)0)                         // ushort[VS_*H_]
#define OFF_W2LO    ((size_t)(VS_*H_/2))
#define OFF_O1HI    (OFF_OUT1 + SZ_OUT1)                // ushort[TD_*B_*H_]
#define OFF_O1LO    (OFF_O1HI + (size_t)(TD_*B_*H_/2))

// LDS geometry for recurrence: k-blocks of 64 floats @ stride 68
#define RSTR 548
#define KBLK 68

__device__ __forceinline__ u32x4 load_u4_cc(const unsigned* p) {
  u32x4 v;
  asm volatile("global_load_dwordx4 %0, %1, off sc0 sc1" : "=v"(v) : "v"(p) : "memory");
  return v;
}

__device__ __forceinline__ float dot4(f32x4 a, f32x4 b) {
  return a.x * b.x + a.y * b.y + a.z * b.z + a.w * b.w;
}

// bf16 round-to-nearest-even
__device__ __forceinline__ unsigned short f2bf(float f) {
  unsigned u = __float_as_uint(f);
  return (unsigned short)((u + 0x7fffu + ((u >> 16) & 1u)) >> 16);
}
__device__ __forceinline__ float bf2f(unsigned short h) {
  return __uint_as_float(((unsigned)h) << 16);
}

// ---------------- persistent GRU-chain kernel, barrier-free, gx pipelined ----------------
// 256 WGs: dom = w>>5 (4 batches), jg = w&31 (16 j-values).
// Schedule per step: [poll h_s, scatter] sync1 [h-dots, red write] sync2
// [stage x_{s+1} || tail: gates from red+red2, publish h_{s+1}] sync3
// [weight switch at S_; acx(s+1) -> red2]   <- fills the straggler-wait window
__global__ __launch_bounds__(WGS)
void recurrence_kernel(const int* __restrict__ mc, const int* __restrict__ ms,
                       const float* __restrict__ enc_emb,
                       const float* __restrict__ eWih, const float* __restrict__ eBih,
                       const float* __restrict__ dec_emb,
                       const float* __restrict__ dWih, const float* __restrict__ dBih,
                       const float* __restrict__ eWhh, const float* __restrict__ eBhh,
                       const float* __restrict__ dWhh, const float* __restrict__ dBhh,
                       float* __restrict__ enc_out,
                       float* __restrict__ hbuf,
                       float* __restrict__ Cmat)
{
  __shared__ float hlds[4 * RSTR];    //  8768 B
  __shared__ float xlds[4 * 256];     //  4096 B
  __shared__ float red[768];          //  h partials  [wave4][jl16][g3][b4]
  __shared__ float red2[768];         //  gx partials

  const int t   = threadIdx.x;
  const int w   = blockIdx.x;
  const int dom = w >> 5;
  const int jg  = w & (JGN - 1);
  const int kh  = t >> 4;             // 0..15
  const int j   = (jg << 4) + (t & 15);
  const int bt_ = t >> 4;             // tail batch (t<64): 0..3
  const int b_g = (dom << 2) + bt_;
  const int xb  = t >> 6, xc = t & 63;           // x staging role
  const int xb_g = (dom << 2) + xb;

  float* hdom = hbuf + (size_t)dom * (2 * HBDW);

  int rr[3], kb[3];
  #pragma unroll
  for (int i = 0; i < 3; ++i) {
    int g = i * 1024 + (t << 2);
    int blk = g / 80;
    rr[i] = g - blk * 80;
    kb[i] = blk << 4;
  }

  f32x4 whh[3][8];
  auto load_whh = [&](const float* __restrict__ W) {
    #pragma unroll
    for (int g = 0; g < 3; ++g)
      #pragma unroll
      for (int c = 0; c < 8; ++c)
        whh[g][c] = *(const f32x4*)(W + (size_t)(g * H_ + j) * H_ + (kh << 5) + (c << 2));
  };
  f32x4 wih[3][4];
  auto load_wih = [&](const float* __restrict__ W) {
    #pragma unroll
    for (int g = 0; g < 3; ++g)
      #pragma unroll
      for (int c = 0; c < 4; ++c)
        wih[g][c] = *(const f32x4*)(W + (size_t)(g * H_ + j) * DE_ + (kh << 4) + (c << 2));
  };
  load_whh(eWhh);
  load_wih(eWih);

  float bhr = 0.f, bhz = 0.f, bhn = 0.f, bxr = 0.f, bxz = 0.f, bxn = 0.f;
  if (t < 64) {
    bhr = eBhh[j]; bhz = eBhh[H_ + j]; bhn = eBhh[2 * H_ + j];
    bxr = eBih[j]; bxz = eBih[H_ + j]; bxn = eBih[2 * H_ + j];
  }

  auto stage_x = [&](int s) {
    const bool enc = (s < S_);
    int tok = enc ? mc[xb_g * S_ + s] : ms[xb_g * L_ + (s - S_)];
    const float* emb = enc ? enc_emb : dec_emb;
    f32x4 xv = *(const f32x4*)(emb + (size_t)tok * DE_ + (xc << 2));
    *(f32x4*)&xlds[xb * 256 + (xc << 2)] = xv;
  };

  auto compute_acx = [&]() {
    float acx[3][4];
    #pragma unroll
    for (int g = 0; g < 3; ++g)
      #pragma unroll
      for (int b = 0; b < 4; ++b) acx[g][b] = 0.f;
    #pragma unroll
    for (int b = 0; b < 4; ++b) {
      const float* xp = &xlds[b * 256 + (kh << 4)];
      #pragma unroll
      for (int c = 0; c < 4; ++c) {
        f32x4 xv = *(const f32x4*)(xp + (c << 2));
        acx[0][b] += dot4(wih[0][c], xv);
        acx[1][b] += dot4(wih[1][c], xv);
        acx[2][b] += dot4(wih[2][c], xv);
      }
    }
    #pragma unroll
    for (int g = 0; g < 3; ++g)
      #pragma unroll
      for (int b = 0; b < 4; ++b) {
        float u = acx[g][b];
        u += __shfl_xor(u, 16); u += __shfl_xor(u, 32);
        acx[g][b] = u;
      }
    if ((t & 48) == 0) {
      const int base = (t >> 6) * 192 + (t & 15) * 12;
      #pragma unroll
      for (int g = 0; g < 3; ++g)
        #pragma unroll
        for (int b = 0; b < 4; ++b)
          red2[base + g * 4 + b] = acx[g][b];
    }
  };

  // prologue: acx(0)
  stage_x(0);
  __syncthreads();
  compute_acx();

  for (int s = 0; s < S_ + TD_; ++s) {
    const bool enc = (s < S_);

    // ---- poll h_s: tagged lines until fresh, scatter to LDS ----
    {
      const unsigned* hb = (const unsigned*)(hdom + (size_t)(s & 1) * HBDW);
      const unsigned tagreq = (unsigned)s;
      u32x4 v0, v1, v2;
      while (true) {
        v0 = load_u4_cc(hb + 0 * 1024 + (t << 2));
        v1 = load_u4_cc(hb + 1 * 1024 + (t << 2));
        if (t < 128) v2 = load_u4_cc(hb + 2 * 1024 + (t << 2));
        asm volatile("s_waitcnt vmcnt(0)" ::: "memory");
        bool ok = true;
        if ((rr[0] & 15) == 0) ok &= ((unsigned)v0.x >= tagreq);
        if ((rr[1] & 15) == 0) ok &= ((unsigned)v1.x >= tagreq);
        if (t < 128 && (rr[2] & 15) == 0) ok &= ((unsigned)v2.x >= tagreq);
        if (__all(ok)) break;
        __builtin_amdgcn_s_sleep(1);
      }
      #define SCAT(vv, ii) { \
        _Pragma("unroll") \
        for (int d = 0; d < 4; ++d) { \
          int pos = rr[ii] + d; \
          if ((pos & 15) != 0) { \
            int p = pos - 1 - (pos >> 4); \
            if (p < 64) { \
              int bb = p >> 4, k = kb[ii] + (p & 15); \
              hlds[bb * RSTR + ((k >> 6) * KBLK) + (k & 63)] = __uint_as_float(vv[d]); \
            } } } }
      SCAT(v0, 0) SCAT(v1, 1)
      if (t < 128) { SCAT(v2, 2) }
      #undef SCAT
    }
    __syncthreads();   // sync1: hlds + red2(s) ready

    // ---- h-dots only: 16 j x 3 gates x 32 k x 4 batches ----
    {
      float acc[3][4];
      #pragma unroll
      for (int g = 0; g < 3; ++g)
        #pragma unroll
        for (int b = 0; b < 4; ++b) acc[g][b] = 0.f;
      const int hoff = (kh >> 1) * KBLK + (kh & 1) * 32;
      #pragma unroll
      for (int b = 0; b < 4; ++b) {
        const float* hp = &hlds[b * RSTR + hoff];
        #pragma unroll
        for (int c = 0; c < 8; ++c) {
          f32x4 hv = *(const f32x4*)(hp + (c << 2));
          acc[0][b] += dot4(whh[0][c], hv);
          acc[1][b] += dot4(whh[1][c], hv);
          acc[2][b] += dot4(whh[2][c], hv);
        }
      }
      #pragma unroll
      for (int g = 0; g < 3; ++g)
        #pragma unroll
        for (int b = 0; b < 4; ++b) {
          float v = acc[g][b];
          v += __shfl_xor(v, 16); v += __shfl_xor(v, 32);
          acc[g][b] = v;
        }
      if ((t & 48) == 0) {
        const int base = (t >> 6) * 192 + (t & 15) * 12;
        #pragma unroll
        for (int g = 0; g < 3; ++g)
          #pragma unroll
          for (int b = 0; b < 4; ++b)
            red[base + g * 4 + b] = acc[g][b];
      }
    }
    __syncthreads();   // sync2: red ready

    // stage x_{s+1} (overlaps tail; xlds(s) consumed last iteration)
    if (s + 1 < S_ + TD_) stage_x(s + 1);

    // ---- tail (t<64): combine red+red2, gate math, publish ----
    if (t < 64) {
      float ar = 0.f, az = 0.f, an = 0.f, xr = 0.f, xz = 0.f, xn = 0.f;
      #pragma unroll
      for (int ww = 0; ww < 4; ++ww) {
        const int base = ww * 192 + (t & 15) * 12 + bt_;
        ar += red[base];      az += red[base + 4];  an += red[base + 8];
        xr += red2[base];     xz += red2[base + 4]; xn += red2[base + 8];
      }
      float gxr = xr + bxr, gxz = xz + bxz, gxn = xn + bxn;
      float rg = 1.f / (1.f + expf(-(gxr + ar + bhr)));
      float zg = 1.f / (1.f + expf(-(gxz + az + bhz)));
      float ng = tanhf(gxn + rg * (an + bhn));
      float hprev = hlds[bt_ * RSTR + ((j >> 6) * KBLK) + (j & 63)];
      float hn = (1.f - zg) * ng + zg * hprev;
      if (enc) enc_out[((size_t)b_g * S_ + s) * H_ + j] = hn;
      else     Cmat[((size_t)(s - S_) * B_ + b_g) * (2 * H_) + H_ + j] = hn;

      unsigned* pb = (unsigned*)(hdom + (size_t)((s + 1) & 1) * HBDW) + jg * 80;
      const unsigned tagv = (unsigned)(s + 1);
      float vA = __shfl(hn, (t - 1 - (t >> 4)) & 63);
      unsigned valA = ((t & 15) == 0) ? tagv : __float_as_uint(vA);
      __hip_atomic_store(pb + t, valA, __ATOMIC_RELAXED, __HIP_MEMORY_SCOPE_AGENT);
      float vB = __shfl(hn, (59 + t) & 63);
      if (t < 16) {
        unsigned valB = (t == 0) ? tagv : __float_as_uint(vB);
        __hip_atomic_store(pb + 64 + t, valB, __ATOMIC_RELAXED, __HIP_MEMORY_SCOPE_AGENT);
      }
    }
    __syncthreads();   // sync3: xlds(s+1) ready; red2/red free

    if (s + 1 < S_ + TD_) {
      if (s + 1 == S_) {    // switch to decoder weights/biases
        load_whh(dWhh);
        load_wih(dWih);
        if (t < 64) {
          bhr = dBhh[j]; bhz = dBhh[H_ + j]; bhn = dBhh[2 * H_ + j];
          bxr = dBih[j]; bxz = dBih[H_ + j]; bxn = dBih[2 * H_ + j];
        }
      }
      compute_acx();        // acx(s+1) -> red2, fills straggler-wait window
    }
  }
}

// ---------------- attention: 4 td per WG, enc_out read once per phase ----------------
__global__ __launch_bounds__(WGS)
void attention_kernel(const float* __restrict__ enc_out,
                      float* __restrict__ Cmat)
{
  const int blk = blockIdx.x;           // b*13 + chunk
  const int b = blk / 13, ch = blk % 13;
  const int t = threadIdx.x;
  __shared__ float hlds[TDG][512];      // 8 KB
  __shared__ float p[TDG][256];         // 4 KB

  // load h for 4 td (clamp invalid td to 48; results discarded)
  for (int idx = t; idx < TDG * 128; idx += WGS) {
    int u = idx >> 7, kq = (idx & 127) << 2;
    int td = ch * TDG + u; if (td >= TD_) td = TD_ - 1;
    *(f32x4*)&hlds[u][kq] =
        *(const f32x4*)(Cmat + ((size_t)td * B_ + b) * (2 * H_) + H_ + kq);
  }
  __syncthreads();

  // scores: thread t = row i; one pass over enc_out[b], 4 dots
  float sv[TDG] = {0.f, 0.f, 0.f, 0.f};
  if (t < S_) {
    const float* eo = enc_out + ((size_t)b * S_ + t) * H_;
    for (int k = 0; k < H_; k += 4) {
      f32x4 e = *(const f32x4*)(eo + k);
      #pragma unroll
      for (int u = 0; u < TDG; ++u) {
        f32x4 hv = *(const f32x4*)&hlds[u][k];
        sv[u] += e.x * hv.x + e.y * hv.y + e.z * hv.z + e.w * hv.w;
      }
    }
  }
  #pragma unroll
  for (int u = 0; u < TDG; ++u) p[u][t] = (t < S_) ? sv[u] : -1e30f;
  __syncthreads();

  // softmax: wave wv owns td wv (shfl-only reduction)
  {
    const int wv = t >> 6, l = t & 63;
    float m = fmaxf(fmaxf(p[wv][l], p[wv][l + 64]),
                    fmaxf(p[wv][l + 128], p[wv][l + 192]));
    for (int o = 32; o; o >>= 1) m = fmaxf(m, __shfl_xor(m, o));
    float e0 = expf(p[wv][l] - m),       e1 = expf(p[wv][l + 64] - m);
    float e2 = expf(p[wv][l + 128] - m), e3 = expf(p[wv][l + 192] - m);
    float ssum = (e0 + e1) + (e2 + e3);
    for (int o = 32; o; o >>= 1) ssum += __shfl_xor(ssum, o);
    float inv = 1.f / ssum;
    p[wv][l] = e0 * inv; p[wv][l + 64] = e1 * inv;
    p[wv][l + 128] = e2 * inv; p[wv][l + 192] = e3 * inv;
  }
  __syncthreads();

  // ctx: thread owns dims 2t,2t+1; one coalesced pass, 4 accumulators
  float ax[TDG] = {0.f, 0.f, 0.f, 0.f}, ay[TDG] = {0.f, 0.f, 0.f, 0.f};
  const float* eo = enc_out + (size_t)b * S_ * H_ + (t << 1);
  for (int i = 0; i < S_; ++i) {
    float2 v = *(const float2*)(eo + (size_t)i * H_);
    #pragma unroll
    for (int u = 0; u < TDG; ++u) {
      float pi = p[u][i];
      ax[u] += pi * v.x; ay[u] += pi * v.y;
    }
  }
  #pragma unroll
  for (int u = 0; u < TDG; ++u) {
    int td = ch * TDG + u;
    if (td < TD_) {
      float* cd = Cmat + ((size_t)td * B_ + b) * (2 * H_) + (t << 1);
      cd[0] = ax[u]; cd[1] = ay[u];
    }
  }
}

// ---------------- fc1: 64x64 fp32 GEMM, relu + bf16-split epilogue ----------------
// M=1568, N=512, K=1024; grid (8, 25) = 200 WGs
__launch_bounds__(WGS)
__global__ void gemm64_fc1(const float* __restrict__ A,
                           const float* __restrict__ Bw,
                           const float* __restrict__ bias,
                           unsigned short* __restrict__ Ohi,
                           unsigned short* __restrict__ Olo)
{
  const int M = TD_ * B_, N = H_, K = 2 * H_;
  const int BK = 16;
  __shared__ float As[BK][64];
  __shared__ float Bs[BK][64];
  const int m0 = blockIdx.y * 64, n0 = blockIdx.x * 64;
  const int t = threadIdx.x;
  const int tx = t & 15, ty = t >> 4;
  float acc[4][4] = {{0.f}};

  const int row = t >> 2, kk = (t & 3) * 4;
  for (int k0 = 0; k0 < K; k0 += BK) {
    {
      int m = m0 + row;
      f32x4 v = {0.f, 0.f, 0.f, 0.f};
      if (m < M) v = *(const f32x4*)(A + (size_t)m * K + k0 + kk);
      As[kk][row] = v.x; As[kk + 1][row] = v.y; As[kk + 2][row] = v.z; As[kk + 3][row] = v.w;
      int n = n0 + row;
      f32x4 wv = *(const f32x4*)(Bw + (size_t)n * K + k0 + kk);
      Bs[kk][row] = wv.x; Bs[kk + 1][row] = wv.y; Bs[kk + 2][row] = wv.z; Bs[kk + 3][row] = wv.w;
    }
    __syncthreads();
    #pragma unroll
    for (int k = 0; k < BK; ++k) {
      float a[4], bq[4];
      *(f32x4*)a  = *(const f32x4*)&As[k][ty * 4];
      *(f32x4*)bq = *(const f32x4*)&Bs[k][tx * 4];
      #pragma unroll
      for (int i = 0; i < 4; ++i)
        #pragma unroll
        for (int jj = 0; jj < 4; ++jj)
          acc[i][jj] += a[i] * bq[jj];
    }
    __syncthreads();
  }

  #pragma unroll
  for (int i = 0; i < 4; ++i) {
    int m = m0 + ty * 4 + i;
    if (m >= M) continue;
    u16x4 hv, lv;
    #pragma unroll
    for (int jj = 0; jj < 4; ++jj) {
      int n = n0 + tx * 4 + jj;
      float v = fmaxf(acc[i][jj] + bias[n], 0.f);
      unsigned short hb = f2bf(v);
      hv[jj] = hb;
      lv[jj] = f2bf(v - bf2f(hb));
    }
    size_t o = (size_t)m * H_ + n0 + tx * 4;
    *(u16x4*)(Ohi + o) = hv;
    *(u16x4*)(Olo + o) = lv;
  }
}

// ---------------- fp32 -> bf16 hi/lo split (W2) ----------------
__global__ __launch_bounds__(WGS)
void cvt_split(const float* __restrict__ x, unsigned short* __restrict__ hi,
               unsigned short* __restrict__ lo, int n4)
{
  int i = blockIdx.x * WGS + threadIdx.x;
  if (i >= n4) return;
  f32x4 v = *(const f32x4*)(x + (size_t)i * 4);
  u16x4 h, l;
  #pragma unroll
  for (int d = 0; d < 4; ++d) {
    unsigned short hb = f2bf(v[d]);
    h[d] = hb;
    l[d] = f2bf(v[d] - bf2f(hb));
  }
  *(u16x4*)(hi + (size_t)i * 4) = h;
  *(u16x4*)(lo + (size_t)i * 4) = l;
}

// ---------------- MFMA bf16x3 vocab projection, 256x128 tile ----------------
// Tile 256(m) x 128(n), BK=32; 4 waves, wave grid 2x2 (each 128m x 64n).
// Single-buffered 48KB LDS + register prefetch; swizzle slot = c ^ ((row>>1)&3)
// on both write and read (proven in round 9).
__global__ __launch_bounds__(WGS, 1)
void gemm_mfma_out(const unsigned short* __restrict__ Ahi,
                   const unsigned short* __restrict__ Alo,
                   const unsigned short* __restrict__ Bhi,
                   const unsigned short* __restrict__ Blo,
                   const float* __restrict__ bias,
                   float* __restrict__ out)
{
  __shared__ char smem[49152];   // Ahi 16K | Alo 16K | Bhi 8K | Blo 8K
  const int t = threadIdx.x;
  const int l = t & 63, wv = t >> 6;
  const int r = l & 15, q = l >> 4;
  const int m0 = blockIdx.x * 256;
  const int n0 = blockIdx.y * 128;
  const int M = TD_ * B_, N = VS_, K = H_;
  const int wm = (wv >> 1) * 128;
  const int wn = (wv & 1) * 64;

  int aswz[4]; size_t aoff[4];
  #pragma unroll
  for (int i = 0; i < 4; ++i) {
    int ca = i * 256 + t;               // 0..1023
    int row = ca >> 2, cc = ca & 3;
    aswz[i] = row * 64 + ((cc ^ ((row >> 1) & 3)) << 4);
    int gm = m0 + row; if (gm >= M) gm = M - 1;
    aoff[i] = (size_t)gm * K + cc * 8;
  }
  int bswz[2]; size_t boff[2];
  #pragma unroll
  for (int i = 0; i < 2; ++i) {
    int cb = i * 256 + t;               // 0..511
    int row = cb >> 2, cc = cb & 3;
    bswz[i] = row * 64 + ((cc ^ ((row >> 1) & 3)) << 4);
    int gn = n0 + row; if (gn >= N) gn = N - 1;
    boff[i] = (size_t)gn * K + cc * 8;
  }

  u32x4 rg[12];
  auto gload = [&](int k0) {
    #pragma unroll
    for (int i = 0; i < 4; ++i) rg[i]     = *(const u32x4*)(Ahi + aoff[i] + k0);
    #pragma unroll
    for (int i = 0; i < 4; ++i) rg[4 + i] = *(const u32x4*)(Alo + aoff[i] + k0);
    #pragma unroll
    for (int i = 0; i < 2; ++i) rg[8 + i] = *(const u32x4*)(Bhi + boff[i] + k0);
    #pragma unroll
    for (int i = 0; i < 2; ++i) rg[10 + i] = *(const u32x4*)(Blo + boff[i] + k0);
  };
  auto swrite = [&]() {
    #pragma unroll
    for (int i = 0; i < 4; ++i) *(u32x4*)(smem + aswz[i]) = rg[i];
    #pragma unroll
    for (int i = 0; i < 4; ++i) *(u32x4*)(smem + 16384 + aswz[i]) = rg[4 + i];
    #pragma unroll
    for (int i = 0; i < 2; ++i) *(u32x4*)(smem + 32768 + bswz[i]) = rg[8 + i];
    #pragma unroll
    for (int i = 0; i < 2; ++i) *(u32x4*)(smem + 40960 + bswz[i]) = rg[10 + i];
  };

  int afo[8], bfo[4];
  #pragma unroll
  for (int fi = 0; fi < 8; ++fi) {
    int ra = wm + fi * 16 + r;
    afo[fi] = ra * 64 + ((q ^ ((ra >> 1) & 3)) << 4);
  }
  #pragma unroll
  for (int nj = 0; nj < 4; ++nj) {
    int rb = wn + nj * 16 + r;
    bfo[nj] = rb * 64 + ((q ^ ((rb >> 1) & 3)) << 4);
  }

  f32x4 acc[8][4];
  #pragma unroll
  for (int fi = 0; fi < 8; ++fi)
    #pragma unroll
    for (int nj = 0; nj < 4; ++nj) acc[fi][nj] = (f32x4){0.f, 0.f, 0.f, 0.f};

  gload(0);
  swrite();
  __syncthreads();
  const int NS = K / 32;   // 16
  for (int s = 0; s < NS; ++s) {
    if (s + 1 < NS) gload((s + 1) * 32);
    s16x8 bh[4], bl[4];
    #pragma unroll
    for (int nj = 0; nj < 4; ++nj) {
      bh[nj] = *(const s16x8*)(smem + 32768 + bfo[nj]);
      bl[nj] = *(const s16x8*)(smem + 40960 + bfo[nj]);
    }
    #pragma unroll
    for (int fi = 0; fi < 8; ++fi) {
      s16x8 ah = *(const s16x8*)(smem + afo[fi]);
      s16x8 al = *(const s16x8*)(smem + 16384 + afo[fi]);
      #pragma unroll
      for (int nj = 0; nj < 4; ++nj) {
        acc[fi][nj] = __builtin_amdgcn_mfma_f32_16x16x32_bf16(ah, bh[nj], acc[fi][nj], 0, 0, 0);
        acc[fi][nj] = __builtin_amdgcn_mfma_f32_16x16x32_bf16(ah, bl[nj], acc[fi][nj], 0, 0, 0);
        acc[fi][nj] = __builtin_amdgcn_mfma_f32_16x16x32_bf16(al, bh[nj], acc[fi][nj], 0, 0, 0);
      }
    }
    __syncthreads();
    if (s + 1 < NS) { swrite(); __syncthreads(); }
  }

  // epilogue: C col = lane&15 (n), row = (lane>>4)*4+e (m)
  #pragma unroll
  for (int nj = 0; nj < 4; ++nj) {
    int n = n0 + wn + nj * 16 + r;
    if (n >= N) continue;
    float bv = bias[n];
    #pragma unroll
    for (int fi = 0; fi < 8; ++fi) {
      #pragma unroll
      for (int e = 0; e < 4; ++e) {
        int m = m0 + wm + fi * 16 + q * 4 + e;
        if (m < M) {
          int bidx = m & 31, td = m >> 5;
          out[((size_t)bidx * TD_ + td) * (size_t)N + n] = acc[fi][nj][e] + bv;
        }
      }
    }
  }
}

// ---------------- launch ----------------
extern "C" void kernel_launch(void* const* d_in, const int* in_sizes, int n_in,
                              void* d_out, int out_size, void* d_ws, size_t ws_size,
                              hipStream_t stream) {
  const int*   method_code    = (const int*)d_in[0];
  const int*   method_summary = (const int*)d_in[1];
  const float* enc_emb = (const float*)d_in[3];
  const float* enc_Wih = (const float*)d_in[4];
  const float* enc_Whh = (const float*)d_in[5];
  const float* enc_bih = (const float*)d_in[6];
  const float* enc_bhh = (const float*)d_in[7];
  const float* dec_emb = (const float*)d_in[8];
  const float* dec_Wih = (const float*)d_in[9];
  const float* dec_Whh = (const float*)d_in[10];
  const float* dec_bih = (const float*)d_in[11];
  const float* dec_bhh = (const float*)d_in[12];
  const float* W1 = (const float*)d_in[13];
  const float* b1 = (const float*)d_in[14];
  const float* W2 = (const float*)d_in[15];
  const float* b2 = (const float*)d_in[16];

  float* ws      = (float*)d_ws;
  float* enc_out = ws + OFF_ENC_OUT;
  float* hbuf    = ws + OFF_HBUF;
  float* Cmat    = ws + OFF_CMAT;
  unsigned short* W2hi = (unsigned short*)(ws + OFF_W2HI);
  unsigned short* W2lo = (unsigned short*)(ws + OFF_W2LO);
  unsigned short* O1hi = (unsigned short*)(ws + OFF_O1HI);
  unsigned short* O1lo = (unsigned short*)(ws + OFF_O1LO);

  // reset h exchange buffers (tags=0 == h_0 valid, payload zeros) every call
  hipMemsetAsync(hbuf, 0, SZ_HBUF * sizeof(float), stream);

  dim3 blk(WGS);

  // persistent GRU chains (gx pipelined off critical path)
  recurrence_kernel<<<NWGR, blk, 0, stream>>>(
      method_code, method_summary,
      enc_emb, enc_Wih, enc_bih,
      dec_emb, dec_Wih, dec_bih,
      enc_Whh, enc_bhh, dec_Whh, dec_bhh,
      enc_out, hbuf, Cmat);

  // attention: 4 td per WG, 416 WGs
  attention_kernel<<<B_ * 13, blk, 0, stream>>>(enc_out, Cmat);

  // W2 bf16 split (overlays now-dead enc_out region; runs after attention)
  cvt_split<<<(VS_ * H_ / 4 + WGS - 1) / WGS, blk, 0, stream>>>(
      W2, W2hi, W2lo, VS_ * H_ / 4);

  // fc1: relu(Cmat @ W1^T + b1) -> bf16 hi/lo, 200 WGs
  gemm64_fc1<<<dim3(H_ / 64, (TD_ * B_ + 63) / 64), blk, 0, stream>>>(
      Cmat, W1, b1, O1hi, O1lo);

  // vocab projection via 3-term bf16 MFMA, 256x128 tile
  gemm_mfma_out<<<dim3((TD_ * B_ + 255) / 256, (VS_ + 127) / 128), blk, 0, stream>>>(
      O1hi, O1lo, W2hi, W2lo, b2, (float*)d_out);
}

// Round 12
// 1395.340 us; speedup vs baseline: 1.3102x; 1.0082x over previous
//
#include <hip/hip_runtime.h>
#include <cmath>

#define WGS  256
#define NWGR 256         // recurrence workgroups (1 per CU)
#define DOMS 16          // independent batch domains (2 batches each)
#define JGN  16          // j-groups per domain (32 j each)
#define HBDW 1280        // dwords per parity buffer per domain (16 blocks x 80)
#define TDG  4           // td per attention WG

typedef float    f32x4 __attribute__((ext_vector_type(4)));
typedef unsigned u32x4 __attribute__((ext_vector_type(4)));
typedef short    s16x8 __attribute__((ext_vector_type(8)));
typedef unsigned short u16x4 __attribute__((ext_vector_type(4)));

// ---------------- sizes ----------------
#define B_   32
#define S_   200
#define L_   50
#define H_   512
#define DE_  256
#define VS_  30000
#define TD_  49          // L-1 decoder steps
#define G3_  1536        // 3*H

// ws layout (float offsets) — same as rounds 10/11 (proven):
#define OFF_ENC_OUT ((size_t)(S_*B_*G3_) + (size_t)(TD_*B_*G3_))   // 12.24M
#define SZ_ENC_OUT  ((size_t)B_*S_*H_)
#define OFF_HBUF    (OFF_ENC_OUT + SZ_ENC_OUT)
#define SZ_HBUF     ((size_t)DOMS*2*HBDW)               // 40960 floats (same)
#define OFF_CMAT    (OFF_HBUF + SZ_HBUF)
#define SZ_CMAT     ((size_t)TD_*B_*2*H_)
#define OFF_OUT1    (OFF_CMAT + SZ_CMAT)
#define SZ_OUT1     ((size_t)TD_*B_*H_)
#define OFF_W2HI    ((size_t)0)                         // ushort[VS_*H_]
#define OFF_W2LO    ((size_t)(VS_*H_/2))
#define OFF_O1HI    (OFF_OUT1 + SZ_OUT1)                // ushort[TD_*B_*H_]
#define OFF_O1LO    (OFF_O1HI + (size_t)(TD_*B_*H_/2))

// LDS geometry for recurrence: k-blocks of 64 floats @ stride 68
#define RSTR 548
#define KBLK 68

__device__ __forceinline__ u32x4 load_u4_cc(const unsigned* p) {
  u32x4 v;
  asm volatile("global_load_dwordx4 %0, %1, off sc0 sc1" : "=v"(v) : "v"(p) : "memory");
  return v;
}

__device__ __forceinline__ float dot4(f32x4 a, f32x4 b) {
  return a.x * b.x + a.y * b.y + a.z * b.z + a.w * b.w;
}

// bf16 round-to-nearest-even
__device__ __forceinline__ unsigned short f2bf(float f) {
  unsigned u = __float_as_uint(f);
  return (unsigned short)((u + 0x7fffu + ((u >> 16) & 1u)) >> 16);
}
__device__ __forceinline__ float bf2f(unsigned short h) {
  return __uint_as_float(((unsigned)h) << 16);
}

// ---------------- persistent GRU-chain kernel, barrier-free, gx pipelined ----------------
// 256 WGs: dom = w>>4 (2 batches), jg = w&15 (32 j-values).
// Compute thread: jl = t&31, kh = t>>5 (8 slices of 64 k for h; 32 k for x).
// Tail t<64: jl = t&31, bt = t>>5. Exchange block (per jg): 80 dw = 5 lines;
// tag at pos%16==0; payload p = pos-1-pos/16 (p<64), p = bt*32+jl = t.
// Published by exactly 2 wave-store instructions -> line-atomic at L3.
__global__ __launch_bounds__(WGS, 1)
void recurrence_kernel(const int* __restrict__ mc, const int* __restrict__ ms,
                       const float* __restrict__ enc_emb,
                       const float* __restrict__ eWih, const float* __restrict__ eBih,
                       const float* __restrict__ dec_emb,
                       const float* __restrict__ dWih, const float* __restrict__ dBih,
                       const float* __restrict__ eWhh, const float* __restrict__ eBhh,
                       const float* __restrict__ dWhh, const float* __restrict__ dBhh,
                       float* __restrict__ enc_out,
                       float* __restrict__ hbuf,
                       float* __restrict__ Cmat)
{
  __shared__ float hlds[2 * RSTR];    // 4384 B: 2 batches x 512
  __shared__ float xlds[2 * 256];     // 2048 B
  __shared__ float red[768];          // [wave4][jl32][g3][b2]
  __shared__ float red2[768];

  const int t   = threadIdx.x;
  const int w   = blockIdx.x;
  const int dom = w >> 4;
  const int jg  = w & (JGN - 1);
  const int jl  = t & 31;
  const int kh  = t >> 5;             // 0..7
  const int j   = (jg << 5) + jl;     // compute/tail j
  const int bt_ = t >> 5;             // tail batch (t<64): 0..1
  const int b_g = (dom << 1) + bt_;
  const int xb  = t >> 6, xc = t & 63;          // x staging (t<128)
  const int xb_g = (dom << 1) + xb;

  float* hdom = hbuf + (size_t)dom * (2 * HBDW);

  // poll constants: chunk0 (all t) g=4t; chunk1 (t<64) g=1024+4t
  int rr0, kb0, rr1, kb1;
  { int g = t << 2; int blk = g / 80; rr0 = g - blk * 80; kb0 = blk << 5; }
  { int g = 1024 + (t << 2); int blk = g / 80; rr1 = g - blk * 80; kb1 = blk << 5; }

  // Whh in VGPRs: 3 gates x 64 k (slice at kh*64)
  f32x4 whh[3][16];
  auto load_whh = [&](const float* __restrict__ W) {
    #pragma unroll
    for (int g = 0; g < 3; ++g)
      #pragma unroll
      for (int c = 0; c < 16; ++c)
        whh[g][c] = *(const f32x4*)(W + (size_t)(g * H_ + j) * H_ + (kh << 6) + (c << 2));
  };
  // Wih in VGPRs: 3 gates x 32 k (slice at kh*32, K=256)
  f32x4 wih[3][8];
  auto load_wih = [&](const float* __restrict__ W) {
    #pragma unroll
    for (int g = 0; g < 3; ++g)
      #pragma unroll
      for (int c = 0; c < 8; ++c)
        wih[g][c] = *(const f32x4*)(W + (size_t)(g * H_ + j) * DE_ + (kh << 5) + (c << 2));
  };
  load_whh(eWhh);
  load_wih(eWih);

  float bhr = 0.f, bhz = 0.f, bhn = 0.f, bxr = 0.f, bxz = 0.f, bxn = 0.f;
  if (t < 64) {
    bhr = eBhh[j]; bhz = eBhh[H_ + j]; bhn = eBhh[2 * H_ + j];
    bxr = eBih[j]; bxz = eBih[H_ + j]; bxn = eBih[2 * H_ + j];
  }

  auto stage_x = [&](int s) {
    if (t < 128) {
      const bool enc = (s < S_);
      int tok = enc ? mc[xb_g * S_ + s] : ms[xb_g * L_ + (s - S_)];
      const float* emb = enc ? enc_emb : dec_emb;
      f32x4 xv = *(const f32x4*)(emb + (size_t)tok * DE_ + (xc << 2));
      *(f32x4*)&xlds[xb * 256 + (xc << 2)] = xv;
    }
  };

  auto compute_acx = [&]() {
    float acx[3][2];
    #pragma unroll
    for (int g = 0; g < 3; ++g) { acx[g][0] = 0.f; acx[g][1] = 0.f; }
    #pragma unroll
    for (int b = 0; b < 2; ++b) {
      const float* xp = &xlds[b * 256 + (kh << 5)];
      #pragma unroll
      for (int c = 0; c < 8; ++c) {
        f32x4 xv = *(const f32x4*)(xp + (c << 2));
        acx[0][b] += dot4(wih[0][c], xv);
        acx[1][b] += dot4(wih[1][c], xv);
        acx[2][b] += dot4(wih[2][c], xv);
      }
    }
    #pragma unroll
    for (int g = 0; g < 3; ++g)
      #pragma unroll
      for (int b = 0; b < 2; ++b) {
        float u = acx[g][b];
        u += __shfl_xor(u, 32);          // kh bit0 = t bit5
        acx[g][b] = u;
      }
    if ((t & 32) == 0) {                 // one lane per (wave, jl)
      const int base = (t >> 6) * 192 + (t & 31) * 6;
      #pragma unroll
      for (int g = 0; g < 3; ++g) {
        red2[base + g * 2 + 0] = acx[g][0];
        red2[base + g * 2 + 1] = acx[g][1];
      }
    }
  };

  // prologue: acx(0)
  stage_x(0);
  __syncthreads();
  compute_acx();

  for (int s = 0; s < S_ + TD_; ++s) {
    const bool enc = (s < S_);

    // ---- poll h_s: tagged lines until fresh, scatter to LDS ----
    {
      const unsigned* hb = (const unsigned*)(hdom + (size_t)(s & 1) * HBDW);
      const unsigned tagreq = (unsigned)s;
      u32x4 v0, v1;
      while (true) {
        v0 = load_u4_cc(hb + (t << 2));
        if (t < 64) v1 = load_u4_cc(hb + 1024 + (t << 2));
        asm volatile("s_waitcnt vmcnt(0)" ::: "memory");
        bool ok = true;
        if ((rr0 & 15) == 0) ok &= ((unsigned)v0.x >= tagreq);
        if (t < 64 && (rr1 & 15) == 0) ok &= ((unsigned)v1.x >= tagreq);
        if (__all(ok)) break;
        __builtin_amdgcn_s_sleep(1);
      }
      #define SCAT(vv, rrX, kbX) { \
        _Pragma("unroll") \
        for (int d = 0; d < 4; ++d) { \
          int pos = rrX + d; \
          if ((pos & 15) != 0) { \
            int p = pos - 1 - (pos >> 4); \
            if (p < 64) { \
              int bb = p >> 5, k = kbX + (p & 31); \
              hlds[bb * RSTR + ((k >> 6) * KBLK) + (k & 63)] = __uint_as_float(vv[d]); \
            } } } }
      SCAT(v0, rr0, kb0)
      if (t < 64) { SCAT(v1, rr1, kb1) }
      #undef SCAT
    }
    __syncthreads();   // sync1: hlds + red2(s) ready

    // ---- h-dots: 32 j x 3 gates x 64 k x 2 batches (LDS reads broadcast) ----
    {
      float acc[3][2];
      #pragma unroll
      for (int g = 0; g < 3; ++g) { acc[g][0] = 0.f; acc[g][1] = 0.f; }
      #pragma unroll
      for (int b = 0; b < 2; ++b) {
        const float* hp = &hlds[b * RSTR + kh * KBLK];
        #pragma unroll
        for (int c = 0; c < 16; ++c) {
          f32x4 hv = *(const f32x4*)(hp + (c << 2));
          acc[0][b] += dot4(whh[0][c], hv);
          acc[1][b] += dot4(whh[1][c], hv);
          acc[2][b] += dot4(whh[2][c], hv);
        }
      }
      #pragma unroll
      for (int g = 0; g < 3; ++g)
        #pragma unroll
        for (int b = 0; b < 2; ++b) {
          float v = acc[g][b];
          v += __shfl_xor(v, 32);
          acc[g][b] = v;
        }
      if ((t & 32) == 0) {
        const int base = (t >> 6) * 192 + (t & 31) * 6;
        #pragma unroll
        for (int g = 0; g < 3; ++g) {
          red[base + g * 2 + 0] = acc[g][0];
          red[base + g * 2 + 1] = acc[g][1];
        }
      }
    }
    __syncthreads();   // sync2: red ready

    // stage x_{s+1} (overlaps tail; xlds(s) consumed by acx(s) last iter)
    if (s + 1 < S_ + TD_) stage_x(s + 1);

    // ---- tail (t<64): combine red+red2, gate math, publish ----
    if (t < 64) {
      const int base0 = (t & 31) * 6 + bt_;
      float ar = red[base0] + red[192 + base0] + red[384 + base0] + red[576 + base0];
      float az = red[base0 + 2] + red[192 + base0 + 2] + red[384 + base0 + 2] + red[576 + base0 + 2];
      float an = red[base0 + 4] + red[192 + base0 + 4] + red[384 + base0 + 4] + red[576 + base0 + 4];
      float xr = red2[base0] + red2[192 + base0] + red2[384 + base0] + red2[576 + base0];
      float xz = red2[base0 + 2] + red2[192 + base0 + 2] + red2[384 + base0 + 2] + red2[576 + base0 + 2];
      float xn = red2[base0 + 4] + red2[192 + base0 + 4] + red2[384 + base0 + 4] + red2[576 + base0 + 4];
      float gxr = xr + bxr, gxz = xz + bxz, gxn = xn + bxn;
      float rg = 1.f / (1.f + expf(-(gxr + ar + bhr)));
      float zg = 1.f / (1.f + expf(-(gxz + az + bhz)));
      float ng = tanhf(gxn + rg * (an + bhn));
      float hprev = hlds[bt_ * RSTR + ((j >> 6) * KBLK) + (j & 63)];
      float hn = (1.f - zg) * ng + zg * hprev;
      if (enc) enc_out[((size_t)b_g * S_ + s) * H_ + j] = hn;
      else     Cmat[((size_t)(s - S_) * B_ + b_g) * (2 * H_) + H_ + j] = hn;

      // publish h_{s+1}: payload index p == tail thread index
      unsigned* pb = (unsigned*)(hdom + (size_t)((s + 1) & 1) * HBDW) + jg * 80;
      const unsigned tagv = (unsigned)(s + 1);
      float vA = __shfl(hn, (t - 1 - (t >> 4)) & 63);
      unsigned valA = ((t & 15) == 0) ? tagv : __float_as_uint(vA);
      __hip_atomic_store(pb + t, valA, __ATOMIC_RELAXED, __HIP_MEMORY_SCOPE_AGENT);
      float vB = __shfl(hn, (59 + t) & 63);
      if (t < 16) {
        unsigned valB = (t == 0) ? tagv : __float_as_uint(vB);
        __hip_atomic_store(pb + 64 + t, valB, __ATOMIC_RELAXED, __HIP_MEMORY_SCOPE_AGENT);
      }
    }
    __syncthreads();   // sync3: xlds(s+1) ready; red/red2 free

    if (s + 1 < S_ + TD_) {
      if (s + 1 == S_) {
        load_whh(dWhh);
        load_wih(dWih);
        if (t < 64) {
          bhr = dBhh[j]; bhz = dBhh[H_ + j]; bhn = dBhh[2 * H_ + j];
          bxr = dBih[j]; bxz = dBih[H_ + j]; bxn = dBih[2 * H_ + j];
        }
      }
      compute_acx();        // acx(s+1) -> red2, fills straggler-wait window
    }
  }
}

// ---------------- attention: 4 td per WG (unchanged from round 11) ----------------
__global__ __launch_bounds__(WGS)
void attention_kernel(const float* __restrict__ enc_out,
                      float* __restrict__ Cmat)
{
  const int blk = blockIdx.x;           // b*13 + chunk
  const int b = blk / 13, ch = blk % 13;
  const int t = threadIdx.x;
  __shared__ float hlds[TDG][512];
  __shared__ float p[TDG][256];

  for (int idx = t; idx < TDG * 128; idx += WGS) {
    int u = idx >> 7, kq = (idx & 127) << 2;
    int td = ch * TDG + u; if (td >= TD_) td = TD_ - 1;
    *(f32x4*)&hlds[u][kq] =
        *(const f32x4*)(Cmat + ((size_t)td * B_ + b) * (2 * H_) + H_ + kq);
  }
  __syncthreads();

  float sv[TDG] = {0.f, 0.f, 0.f, 0.f};
  if (t < S_) {
    const float* eo = enc_out + ((size_t)b * S_ + t) * H_;
    for (int k = 0; k < H_; k += 4) {
      f32x4 e = *(const f32x4*)(eo + k);
      #pragma unroll
      for (int u = 0; u < TDG; ++u) {
        f32x4 hv = *(const f32x4*)&hlds[u][k];
        sv[u] += e.x * hv.x + e.y * hv.y + e.z * hv.z + e.w * hv.w;
      }
    }
  }
  #pragma unroll
  for (int u = 0; u < TDG; ++u) p[u][t] = (t < S_) ? sv[u] : -1e30f;
  __syncthreads();

  {
    const int wv = t >> 6, l = t & 63;
    float m = fmaxf(fmaxf(p[wv][l], p[wv][l + 64]),
                    fmaxf(p[wv][l + 128], p[wv][l + 192]));
    for (int o = 32; o; o >>= 1) m = fmaxf(m, __shfl_xor(m, o));
    float e0 = expf(p[wv][l] - m),       e1 = expf(p[wv][l + 64] - m);
    float e2 = expf(p[wv][l + 128] - m), e3 = expf(p[wv][l + 192] - m);
    float ssum = (e0 + e1) + (e2 + e3);
    for (int o = 32; o; o >>= 1) ssum += __shfl_xor(ssum, o);
    float inv = 1.f / ssum;
    p[wv][l] = e0 * inv; p[wv][l + 64] = e1 * inv;
    p[wv][l + 128] = e2 * inv; p[wv][l + 192] = e3 * inv;
  }
  __syncthreads();

  float ax[TDG] = {0.f, 0.f, 0.f, 0.f}, ay[TDG] = {0.f, 0.f, 0.f, 0.f};
  const float* eo = enc_out + (size_t)b * S_ * H_ + (t << 1);
  for (int i = 0; i < S_; ++i) {
    float2 v = *(const float2*)(eo + (size_t)i * H_);
    #pragma unroll
    for (int u = 0; u < TDG; ++u) {
      float pi = p[u][i];
      ax[u] += pi * v.x; ay[u] += pi * v.y;
    }
  }
  #pragma unroll
  for (int u = 0; u < TDG; ++u) {
    int td = ch * TDG + u;
    if (td < TD_) {
      float* cd = Cmat + ((size_t)td * B_ + b) * (2 * H_) + (t << 1);
      cd[0] = ax[u]; cd[1] = ay[u];
    }
  }
}

// ---------------- fc1: 64x64 fp32 GEMM, relu + bf16-split epilogue (unchanged) ----------------
__launch_bounds__(WGS)
__global__ void gemm64_fc1(const float* __restrict__ A,
                           const float* __restrict__ Bw,
                           const float* __restrict__ bias,
                           unsigned short* __restrict__ Ohi,
                           unsigned short* __restrict__ Olo)
{
  const int M = TD_ * B_, N = H_, K = 2 * H_;
  const int BK = 16;
  __shared__ float As[BK][64];
  __shared__ float Bs[BK][64];
  const int m0 = blockIdx.y * 64, n0 = blockIdx.x * 64;
  const int t = threadIdx.x;
  const int tx = t & 15, ty = t >> 4;
  float acc[4][4] = {{0.f}};

  const int row = t >> 2, kk = (t & 3) * 4;
  for (int k0 = 0; k0 < K; k0 += BK) {
    {
      int m = m0 + row;
      f32x4 v = {0.f, 0.f, 0.f, 0.f};
      if (m < M) v = *(const f32x4*)(A + (size_t)m * K + k0 + kk);
      As[kk][row] = v.x; As[kk + 1][row] = v.y; As[kk + 2][row] = v.z; As[kk + 3][row] = v.w;
      int n = n0 + row;
      f32x4 wv = *(const f32x4*)(Bw + (size_t)n * K + k0 + kk);
      Bs[kk][row] = wv.x; Bs[kk + 1][row] = wv.y; Bs[kk + 2][row] = wv.z; Bs[kk + 3][row] = wv.w;
    }
    __syncthreads();
    #pragma unroll
    for (int k = 0; k < BK; ++k) {
      float a[4], bq[4];
      *(f32x4*)a  = *(const f32x4*)&As[k][ty * 4];
      *(f32x4*)bq = *(const f32x4*)&Bs[k][tx * 4];
      #pragma unroll
      for (int i = 0; i < 4; ++i)
        #pragma unroll
        for (int jj = 0; jj < 4; ++jj)
          acc[i][jj] += a[i] * bq[jj];
    }
    __syncthreads();
  }

  #pragma unroll
  for (int i = 0; i < 4; ++i) {
    int m = m0 + ty * 4 + i;
    if (m >= M) continue;
    u16x4 hv, lv;
    #pragma unroll
    for (int jj = 0; jj < 4; ++jj) {
      int n = n0 + tx * 4 + jj;
      float v = fmaxf(acc[i][jj] + bias[n], 0.f);
      unsigned short hb = f2bf(v);
      hv[jj] = hb;
      lv[jj] = f2bf(v - bf2f(hb));
    }
    size_t o = (size_t)m * H_ + n0 + tx * 4;
    *(u16x4*)(Ohi + o) = hv;
    *(u16x4*)(Olo + o) = lv;
  }
}

// ---------------- fp32 -> bf16 hi/lo split (W2, unchanged) ----------------
__global__ __launch_bounds__(WGS)
void cvt_split(const float* __restrict__ x, unsigned short* __restrict__ hi,
               unsigned short* __restrict__ lo, int n4)
{
  int i = blockIdx.x * WGS + threadIdx.x;
  if (i >= n4) return;
  f32x4 v = *(const f32x4*)(x + (size_t)i * 4);
  u16x4 h, l;
  #pragma unroll
  for (int d = 0; d < 4; ++d) {
    unsigned short hb = f2bf(v[d]);
    h[d] = hb;
    l[d] = f2bf(v[d] - bf2f(hb));
  }
  *(u16x4*)(hi + (size_t)i * 4) = h;
  *(u16x4*)(lo + (size_t)i * 4) = l;
}

// ---------------- MFMA bf16x3 vocab projection, 256x128 tile, 2-deep prefetch ----------------
__global__ __launch_bounds__(WGS, 1)
void gemm_mfma_out(const unsigned short* __restrict__ Ahi,
                   const unsigned short* __restrict__ Alo,
                   const unsigned short* __restrict__ Bhi,
                   const unsigned short* __restrict__ Blo,
                   const float* __restrict__ bias,
                   float* __restrict__ out)
{
  __shared__ char smem[49152];   // Ahi 16K | Alo 16K | Bhi 8K | Blo 8K
  const int t = threadIdx.x;
  const int l = t & 63, wv = t >> 6;
  const int r = l & 15, q = l >> 4;
  const int m0 = blockIdx.x * 256;
  const int n0 = blockIdx.y * 128;
  const int M = TD_ * B_, N = VS_, K = H_;
  const int wm = (wv >> 1) * 128;
  const int wn = (wv & 1) * 64;

  int aswz[4]; size_t aoff[4];
  #pragma unroll
  for (int i = 0; i < 4; ++i) {
    int ca = i * 256 + t;
    int row = ca >> 2, cc = ca & 3;
    aswz[i] = row * 64 + ((cc ^ ((row >> 1) & 3)) << 4);
    int gm = m0 + row; if (gm >= M) gm = M - 1;
    aoff[i] = (size_t)gm * K + cc * 8;
  }
  int bswz[2]; size_t boff[2];
  #pragma unroll
  for (int i = 0; i < 2; ++i) {
    int cb = i * 256 + t;
    int row = cb >> 2, cc = cb & 3;
    bswz[i] = row * 64 + ((cc ^ ((row >> 1) & 3)) << 4);
    int gn = n0 + row; if (gn >= N) gn = N - 1;
    boff[i] = (size_t)gn * K + cc * 8;
  }

  u32x4 rgA[12], rgB[12];
  #define GLOAD(rg, k0) { \
    _Pragma("unroll") \
    for (int i = 0; i < 4; ++i) rg[i]     = *(const u32x4*)(Ahi + aoff[i] + (k0)); \
    _Pragma("unroll") \
    for (int i = 0; i < 4; ++i) rg[4 + i] = *(const u32x4*)(Alo + aoff[i] + (k0)); \
    _Pragma("unroll") \
    for (int i = 0; i < 2; ++i) rg[8 + i] = *(const u32x4*)(Bhi + boff[i] + (k0)); \
    _Pragma("unroll") \
    for (int i = 0; i < 2; ++i) rg[10 + i] = *(const u32x4*)(Blo + boff[i] + (k0)); }
  #define SWRITE(rg) { \
    _Pragma("unroll") \
    for (int i = 0; i < 4; ++i) *(u32x4*)(smem + aswz[i]) = rg[i]; \
    _Pragma("unroll") \
    for (int i = 0; i < 4; ++i) *(u32x4*)(smem + 16384 + aswz[i]) = rg[4 + i]; \
    _Pragma("unroll") \
    for (int i = 0; i < 2; ++i) *(u32x4*)(smem + 32768 + bswz[i]) = rg[8 + i]; \
    _Pragma("unroll") \
    for (int i = 0; i < 2; ++i) *(u32x4*)(smem + 40960 + bswz[i]) = rg[10 + i]; }

  int afo[8], bfo[4];
  #pragma unroll
  for (int fi = 0; fi < 8; ++fi) {
    int ra = wm + fi * 16 + r;
    afo[fi] = ra * 64 + ((q ^ ((ra >> 1) & 3)) << 4);
  }
  #pragma unroll
  for (int nj = 0; nj < 4; ++nj) {
    int rb = wn + nj * 16 + r;
    bfo[nj] = rb * 64 + ((q ^ ((rb >> 1) & 3)) << 4);
  }

  f32x4 acc[8][4];
  #pragma unroll
  for (int fi = 0; fi < 8; ++fi)
    #pragma unroll
    for (int nj = 0; nj < 4; ++nj) acc[fi][nj] = (f32x4){0.f, 0.f, 0.f, 0.f};

  // 2-deep pipeline: rgA/rgB hold data for steps s+1 / s+2 while LDS holds s
  GLOAD(rgA, 0)
  SWRITE(rgA)
  GLOAD(rgA, 32)        // step-1 data
  GLOAD(rgB, 64)        // step-2 data
  __syncthreads();
  const int NS = K / 32;   // 16
  for (int s = 0; s < NS; ++s) {
    s16x8 bh[4], bl[4];
    #pragma unroll
    for (int nj = 0; nj < 4; ++nj) {
      bh[nj] = *(const s16x8*)(smem + 32768 + bfo[nj]);
      bl[nj] = *(const s16x8*)(smem + 40960 + bfo[nj]);
    }
    #pragma unroll
    for (int fi = 0; fi < 8; ++fi) {
      s16x8 ah = *(const s16x8*)(smem + afo[fi]);
      s16x8 al = *(const s16x8*)(smem + 16384 + afo[fi]);
      #pragma unroll
      for (int nj = 0; nj < 4; ++nj) {
        acc[fi][nj] = __builtin_amdgcn_mfma_f32_16x16x32_bf16(ah, bh[nj], acc[fi][nj], 0, 0, 0);
        acc[fi][nj] = __builtin_amdgcn_mfma_f32_16x16x32_bf16(ah, bl[nj], acc[fi][nj], 0, 0, 0);
        acc[fi][nj] = __builtin_amdgcn_mfma_f32_16x16x32_bf16(al, bh[nj], acc[fi][nj], 0, 0, 0);
      }
    }
    __syncthreads();
    if (s + 1 < NS) {
      if (s & 1) { SWRITE(rgB) } else { SWRITE(rgA) }   // step s+1 data (aged 2 steps)
      __syncthreads();
      if (s + 3 < NS) {
        if (s & 1) { GLOAD(rgB, (s + 3) * 32) } else { GLOAD(rgA, (s + 3) * 32) }
      }
    }
  }
  #undef GLOAD
  #undef SWRITE

  #pragma unroll
  for (int nj = 0; nj < 4; ++nj) {
    int n = n0 + wn + nj * 16 + r;
    if (n >= N) continue;
    float bv = bias[n];
    #pragma unroll
    for (int fi = 0; fi < 8; ++fi) {
      #pragma unroll
      for (int e = 0; e < 4; ++e) {
        int m = m0 + wm + fi * 16 + q * 4 + e;
        if (m < M) {
          int bidx = m & 31, td = m >> 5;
          out[((size_t)bidx * TD_ + td) * (size_t)N + n] = acc[fi][nj][e] + bv;
        }
      }
    }
  }
}

// ---------------- launch ----------------
extern "C" void kernel_launch(void* const* d_in, const int* in_sizes, int n_in,
                              void* d_out, int out_size, void* d_ws, size_t ws_size,
                              hipStream_t stream) {
  const int*   method_code    = (const int*)d_in[0];
  const int*   method_summary = (const int*)d_in[1];
  const float* enc_emb = (const float*)d_in[3];
  const float* enc_Wih = (const float*)d_in[4];
  const float* enc_Whh = (const float*)d_in[5];
  const float* enc_bih = (const float*)d_in[6];
  const float* enc_bhh = (const float*)d_in[7];
  const float* dec_emb = (const float*)d_in[8];
  const float* dec_Wih = (const float*)d_in[9];
  const float* dec_Whh = (const float*)d_in[10];
  const float* dec_bih = (const float*)d_in[11];
  const float* dec_bhh = (const float*)d_in[12];
  const float* W1 = (const float*)d_in[13];
  const float* b1 = (const float*)d_in[14];
  const float* W2 = (const float*)d_in[15];
  const float* b2 = (const float*)d_in[16];

  float* ws      = (float*)d_ws;
  float* enc_out = ws + OFF_ENC_OUT;
  float* hbuf    = ws + OFF_HBUF;
  float* Cmat    = ws + OFF_CMAT;
  unsigned short* W2hi = (unsigned short*)(ws + OFF_W2HI);
  unsigned short* W2lo = (unsigned short*)(ws + OFF_W2LO);
  unsigned short* O1hi = (unsigned short*)(ws + OFF_O1HI);
  unsigned short* O1lo = (unsigned short*)(ws + OFF_O1LO);

  // reset h exchange buffers (tags=0 == h_0 valid, payload zeros) every call
  hipMemsetAsync(hbuf, 0, SZ_HBUF * sizeof(float), stream);

  dim3 blk(WGS);

  // persistent GRU chains: 16 domains x 16 j-groups
  recurrence_kernel<<<NWGR, blk, 0, stream>>>(
      method_code, method_summary,
      enc_emb, enc_Wih, enc_bih,
      dec_emb, dec_Wih, dec_bih,
      enc_Whh, enc_bhh, dec_Whh, dec_bhh,
      enc_out, hbuf, Cmat);

  // attention: 4 td per WG, 416 WGs
  attention_kernel<<<B_ * 13, blk, 0, stream>>>(enc_out, Cmat);

  // W2 bf16 split (overlays now-dead enc_out region; runs after attention)
  cvt_split<<<(VS_ * H_ / 4 + WGS - 1) / WGS, blk, 0, stream>>>(
      W2, W2hi, W2lo, VS_ * H_ / 4);

  // fc1: relu(Cmat @ W1^T + b1) -> bf16 hi/lo, 200 WGs
  gemm64_fc1<<<dim3(H_ / 64, (TD_ * B_ + 63) / 64), blk, 0, stream>>>(
      Cmat, W1, b1, O1hi, O1lo);

  // vocab projection via 3-term bf16 MFMA, 256x128 tile, 2-deep prefetch
  gemm_mfma_out<<<dim3((TD_ * B_ + 255) / 256, (VS_ + 127) / 128), blk, 0, stream>>>(
      O1hi, O1lo, W2hi, W2lo, b2, (float*)d_out);
}

// Round 15
// 1368.337 us; speedup vs baseline: 1.3361x; 1.0197x over previous
//
#include <hip/hip_runtime.h>
#include <cmath>

#define WGS  256
#define NWGR 256         // recurrence workgroups (1 per CU)
#define DOMS 16          // independent batch domains (2 batches each)
#define JGN  16          // j-groups per domain (32 j each)
#define HBDW 1280        // dwords per parity buffer per domain (16 blocks x 80)
#define TDG  4           // td per attention WG

typedef float    f32x4 __attribute__((ext_vector_type(4)));
typedef unsigned u32x4 __attribute__((ext_vector_type(4)));
typedef short    s16x8 __attribute__((ext_vector_type(8)));
typedef unsigned short u16x4 __attribute__((ext_vector_type(4)));

// ---------------- sizes ----------------
#define B_   32
#define S_   200
#define L_   50
#define H_   512
#define DE_  256
#define VS_  30000
#define TD_  49          // L-1 decoder steps
#define G3_  1536        // 3*H

// ---------------- ws layout (float offsets) ----------------
#define OFF_ENC_OUT ((size_t)(S_*B_*G3_) + (size_t)(TD_*B_*G3_))   // 12.24M
#define SZ_ENC_OUT  ((size_t)B_*S_*H_)
#define OFF_HBUF    (OFF_ENC_OUT + SZ_ENC_OUT)
#define SZ_HBUF     ((size_t)DOMS*2*HBDW)               // 40960 floats
#define OFF_CMAT    (OFF_HBUF + SZ_HBUF)
#define SZ_CMAT     ((size_t)TD_*B_*2*H_)
#define OFF_OUT1    (OFF_CMAT + SZ_CMAT)
#define SZ_OUT1     ((size_t)TD_*B_*H_)
#define OFF_W2HI    ((size_t)0)                         // ushort[VS_*H_]
#define OFF_W2LO    ((size_t)(VS_*H_/2))
#define OFF_O1HI    (OFF_OUT1 + SZ_OUT1)                // ushort[TD_*B_*H_]
#define OFF_O1LO    (OFF_O1HI + (size_t)(TD_*B_*H_/2))

// LDS geometry for recurrence: k-blocks of 64 floats @ stride 68
#define RSTR 548
#define KBLK 68

__device__ __forceinline__ u32x4 load_u4_cc(const unsigned* p) {
  u32x4 v;
  asm volatile("global_load_dwordx4 %0, %1, off sc0 sc1" : "=v"(v) : "v"(p) : "memory");
  return v;
}

__device__ __forceinline__ float dot4(f32x4 a, f32x4 b) {
  return a.x * b.x + a.y * b.y + a.z * b.z + a.w * b.w;
}

// bf16 round-to-nearest-even
__device__ __forceinline__ unsigned short f2bf(float f) {
  unsigned u = __float_as_uint(f);
  return (unsigned short)((u + 0x7fffu + ((u >> 16) & 1u)) >> 16);
}
__device__ __forceinline__ float bf2f(unsigned short h) {
  return __uint_as_float(((unsigned)h) << 16);
}

// ---------------- persistent GRU-chain kernel, barrier-free (round-12 proven) ----------------
// 256 WGs: dom = w>>4 (2 batches), jg = w&15 (32 j-values).
// Compute thread: jl = t&31, kh = t>>5 (8 slices of 64 k for h; 32 k for x).
// Tail t<64: jl = t&31, bt = t>>5. Exchange block (per jg): 80 dw = 5 lines;
// tag at pos%16==0; payload p = pos-1-pos/16 (p<64), p = bt*32+jl = t.
// Published by exactly 2 wave-store instructions -> line-atomic at L3.
__global__ __launch_bounds__(WGS, 1)
void recurrence_kernel(const int* __restrict__ mc, const int* __restrict__ ms,
                       const float* __restrict__ enc_emb,
                       const float* __restrict__ eWih, const float* __restrict__ eBih,
                       const float* __restrict__ dec_emb,
                       const float* __restrict__ dWih, const float* __restrict__ dBih,
                       const float* __restrict__ eWhh, const float* __restrict__ eBhh,
                       const float* __restrict__ dWhh, const float* __restrict__ dBhh,
                       float* __restrict__ enc_out,
                       float* __restrict__ hbuf,
                       float* __restrict__ Cmat)
{
  __shared__ float hlds[2 * RSTR];    // 4384 B: 2 batches x 512
  __shared__ float xlds[2 * 256];     // 2048 B
  __shared__ float red[768];          // [wave4][jl32][g3][b2]
  __shared__ float red2[768];

  const int t   = threadIdx.x;
  const int w   = blockIdx.x;
  const int dom = w >> 4;
  const int jg  = w & (JGN - 1);
  const int jl  = t & 31;
  const int kh  = t >> 5;             // 0..7
  const int j   = (jg << 5) + jl;     // compute/tail j
  const int bt_ = t >> 5;             // tail batch (t<64): 0..1
  const int b_g = (dom << 1) + bt_;
  const int xb  = t >> 6, xc = t & 63;          // x staging (t<128)
  const int xb_g = (dom << 1) + xb;

  float* hdom = hbuf + (size_t)dom * (2 * HBDW);

  // poll constants: chunk0 (all t) g=4t; chunk1 (t<64) g=1024+4t
  int rr0, kb0, rr1, kb1;
  { int g = t << 2; int blk = g / 80; rr0 = g - blk * 80; kb0 = blk << 5; }
  { int g = 1024 + (t << 2); int blk = g / 80; rr1 = g - blk * 80; kb1 = blk << 5; }

  // Whh in VGPRs: 3 gates x 64 k (slice at kh*64)
  f32x4 whh[3][16];
  auto load_whh = [&](const float* __restrict__ W) {
    #pragma unroll
    for (int g = 0; g < 3; ++g)
      #pragma unroll
      for (int c = 0; c < 16; ++c)
        whh[g][c] = *(const f32x4*)(W + (size_t)(g * H_ + j) * H_ + (kh << 6) + (c << 2));
  };
  // Wih in VGPRs: 3 gates x 32 k (slice at kh*32, K=256)
  f32x4 wih[3][8];
  auto load_wih = [&](const float* __restrict__ W) {
    #pragma unroll
    for (int g = 0; g < 3; ++g)
      #pragma unroll
      for (int c = 0; c < 8; ++c)
        wih[g][c] = *(const f32x4*)(W + (size_t)(g * H_ + j) * DE_ + (kh << 5) + (c << 2));
  };
  load_whh(eWhh);
  load_wih(eWih);

  float bhr = 0.f, bhz = 0.f, bhn = 0.f, bxr = 0.f, bxz = 0.f, bxn = 0.f;
  if (t < 64) {
    bhr = eBhh[j]; bhz = eBhh[H_ + j]; bhn = eBhh[2 * H_ + j];
    bxr = eBih[j]; bxz = eBih[H_ + j]; bxn = eBih[2 * H_ + j];
  }

  auto stage_x = [&](int s) {
    if (t < 128) {
      const bool enc = (s < S_);
      int tok = enc ? mc[xb_g * S_ + s] : ms[xb_g * L_ + (s - S_)];
      const float* emb = enc ? enc_emb : dec_emb;
      f32x4 xv = *(const f32x4*)(emb + (size_t)tok * DE_ + (xc << 2));
      *(f32x4*)&xlds[xb * 256 + (xc << 2)] = xv;
    }
  };

  auto compute_acx = [&]() {
    float acx[3][2];
    #pragma unroll
    for (int g = 0; g < 3; ++g) { acx[g][0] = 0.f; acx[g][1] = 0.f; }
    #pragma unroll
    for (int b = 0; b < 2; ++b) {
      const float* xp = &xlds[b * 256 + (kh << 5)];
      #pragma unroll
      for (int c = 0; c < 8; ++c) {
        f32x4 xv = *(const f32x4*)(xp + (c << 2));
        acx[0][b] += dot4(wih[0][c], xv);
        acx[1][b] += dot4(wih[1][c], xv);
        acx[2][b] += dot4(wih[2][c], xv);
      }
    }
    #pragma unroll
    for (int g = 0; g < 3; ++g)
      #pragma unroll
      for (int b = 0; b < 2; ++b) {
        float u = acx[g][b];
        u += __shfl_xor(u, 32);          // kh bit0 = t bit5
        acx[g][b] = u;
      }
    if ((t & 32) == 0) {                 // one lane per (wave, jl)
      const int base = (t >> 6) * 192 + (t & 31) * 6;
      #pragma unroll
      for (int g = 0; g < 3; ++g) {
        red2[base + g * 2 + 0] = acx[g][0];
        red2[base + g * 2 + 1] = acx[g][1];
      }
    }
  };

  // prologue: acx(0)
  stage_x(0);
  __syncthreads();
  compute_acx();

  for (int s = 0; s < S_ + TD_; ++s) {
    const bool enc = (s < S_);

    // ---- poll h_s: tagged lines until fresh, scatter to LDS ----
    {
      const unsigned* hb = (const unsigned*)(hdom + (size_t)(s & 1) * HBDW);
      const unsigned tagreq = (unsigned)s;
      u32x4 v0, v1;
      while (true) {
        v0 = load_u4_cc(hb + (t << 2));
        if (t < 64) v1 = load_u4_cc(hb + 1024 + (t << 2));
        asm volatile("s_waitcnt vmcnt(0)" ::: "memory");
        bool ok = true;
        if ((rr0 & 15) == 0) ok &= ((unsigned)v0.x >= tagreq);
        if (t < 64 && (rr1 & 15) == 0) ok &= ((unsigned)v1.x >= tagreq);
        if (__all(ok)) break;
        __builtin_amdgcn_s_sleep(1);
      }
      #define SCAT(vv, rrX, kbX) { \
        _Pragma("unroll") \
        for (int d = 0; d < 4; ++d) { \
          int pos = rrX + d; \
          if ((pos & 15) != 0) { \
            int p = pos - 1 - (pos >> 4); \
            if (p < 64) { \
              int bb = p >> 5, k = kbX + (p & 31); \
              hlds[bb * RSTR + ((k >> 6) * KBLK) + (k & 63)] = __uint_as_float(vv[d]); \
            } } } }
      SCAT(v0, rr0, kb0)
      if (t < 64) { SCAT(v1, rr1, kb1) }
      #undef SCAT
    }
    __syncthreads();   // sync1: hlds + red2(s) ready

    // ---- h-dots: 32 j x 3 gates x 64 k x 2 batches (LDS reads broadcast) ----
    {
      float acc[3][2];
      #pragma unroll
      for (int g = 0; g < 3; ++g) { acc[g][0] = 0.f; acc[g][1] = 0.f; }
      #pragma unroll
      for (int b = 0; b < 2; ++b) {
        const float* hp = &hlds[b * RSTR + kh * KBLK];
        #pragma unroll
        for (int c = 0; c < 16; ++c) {
          f32x4 hv = *(const f32x4*)(hp + (c << 2));
          acc[0][b] += dot4(whh[0][c], hv);
          acc[1][b] += dot4(whh[1][c], hv);
          acc[2][b] += dot4(whh[2][c], hv);
        }
      }
      #pragma unroll
      for (int g = 0; g < 3; ++g)
        #pragma unroll
        for (int b = 0; b < 2; ++b) {
          float v = acc[g][b];
          v += __shfl_xor(v, 32);
          acc[g][b] = v;
        }
      if ((t & 32) == 0) {
        const int base = (t >> 6) * 192 + (t & 31) * 6;
        #pragma unroll
        for (int g = 0; g < 3; ++g) {
          red[base + g * 2 + 0] = acc[g][0];
          red[base + g * 2 + 1] = acc[g][1];
        }
      }
    }
    __syncthreads();   // sync2: red ready

    // stage x_{s+1} (overlaps tail; xlds(s) consumed by acx(s) last iter)
    if (s + 1 < S_ + TD_) stage_x(s + 1);

    // ---- tail (t<64): combine red+red2, gate math, publish ----
    if (t < 64) {
      const int base0 = (t & 31) * 6 + bt_;
      float ar = red[base0] + red[192 + base0] + red[384 + base0] + red[576 + base0];
      float az = red[base0 + 2] + red[192 + base0 + 2] + red[384 + base0 + 2] + red[576 + base0 + 2];
      float an = red[base0 + 4] + red[192 + base0 + 4] + red[384 + base0 + 4] + red[576 + base0 + 4];
      float xr = red2[base0] + red2[192 + base0] + red2[384 + base0] + red2[576 + base0];
      float xz = red2[base0 + 2] + red2[192 + base0 + 2] + red2[384 + base0 + 2] + red2[576 + base0 + 2];
      float xn = red2[base0 + 4] + red2[192 + base0 + 4] + red2[384 + base0 + 4] + red2[576 + base0 + 4];
      float gxr = xr + bxr, gxz = xz + bxz, gxn = xn + bxn;
      float rg = 1.f / (1.f + expf(-(gxr + ar + bhr)));
      float zg = 1.f / (1.f + expf(-(gxz + az + bhz)));
      float ng = tanhf(gxn + rg * (an + bhn));
      float hprev = hlds[bt_ * RSTR + ((j >> 6) * KBLK) + (j & 63)];
      float hn = (1.f - zg) * ng + zg * hprev;
      if (enc) enc_out[((size_t)b_g * S_ + s) * H_ + j] = hn;
      else     Cmat[((size_t)(s - S_) * B_ + b_g) * (2 * H_) + H_ + j] = hn;

      // publish h_{s+1}: payload index p == tail thread index
      unsigned* pb = (unsigned*)(hdom + (size_t)((s + 1) & 1) * HBDW) + jg * 80;
      const unsigned tagv = (unsigned)(s + 1);
      float vA = __shfl(hn, (t - 1 - (t >> 4)) & 63);
      unsigned valA = ((t & 15) == 0) ? tagv : __float_as_uint(vA);
      __hip_atomic_store(pb + t, valA, __ATOMIC_RELAXED, __HIP_MEMORY_SCOPE_AGENT);
      float vB = __shfl(hn, (59 + t) & 63);
      if (t < 16) {
        unsigned valB = (t == 0) ? tagv : __float_as_uint(vB);
        __hip_atomic_store(pb + 64 + t, valB, __ATOMIC_RELAXED, __HIP_MEMORY_SCOPE_AGENT);
      }
    }
    __syncthreads();   // sync3: xlds(s+1) ready; red/red2 free

    if (s + 1 < S_ + TD_) {
      if (s + 1 == S_) {
        load_whh(dWhh);
        load_wih(dWih);
        if (t < 64) {
          bhr = dBhh[j]; bhz = dBhh[H_ + j]; bhn = dBhh[2 * H_ + j];
          bxr = dBih[j]; bxz = dBih[H_ + j]; bxn = dBih[2 * H_ + j];
        }
      }
      compute_acx();        // acx(s+1) -> red2, fills straggler-wait window
    }
  }
}

// ---------------- attention: 4 td per WG (proven) ----------------
__global__ __launch_bounds__(WGS)
void attention_kernel(const float* __restrict__ enc_out,
                      float* __restrict__ Cmat)
{
  const int blk = blockIdx.x;           // b*13 + chunk
  const int b = blk / 13, ch = blk % 13;
  const int t = threadIdx.x;
  __shared__ float hlds[TDG][512];
  __shared__ float p[TDG][256];

  for (int idx = t; idx < TDG * 128; idx += WGS) {
    int u = idx >> 7, kq = (idx & 127) << 2;
    int td = ch * TDG + u; if (td >= TD_) td = TD_ - 1;
    *(f32x4*)&hlds[u][kq] =
        *(const f32x4*)(Cmat + ((size_t)td * B_ + b) * (2 * H_) + H_ + kq);
  }
  __syncthreads();

  float sv[TDG] = {0.f, 0.f, 0.f, 0.f};
  if (t < S_) {
    const float* eo = enc_out + ((size_t)b * S_ + t) * H_;
    for (int k = 0; k < H_; k += 4) {
      f32x4 e = *(const f32x4*)(eo + k);
      #pragma unroll
      for (int u = 0; u < TDG; ++u) {
        f32x4 hv = *(const f32x4*)&hlds[u][k];
        sv[u] += e.x * hv.x + e.y * hv.y + e.z * hv.z + e.w * hv.w;
      }
    }
  }
  #pragma unroll
  for (int u = 0; u < TDG; ++u) p[u][t] = (t < S_) ? sv[u] : -1e30f;
  __syncthreads();

  {
    const int wv = t >> 6, l = t & 63;
    float m = fmaxf(fmaxf(p[wv][l], p[wv][l + 64]),
                    fmaxf(p[wv][l + 128], p[wv][l + 192]));
    for (int o = 32; o; o >>= 1) m = fmaxf(m, __shfl_xor(m, o));
    float e0 = expf(p[wv][l] - m),       e1 = expf(p[wv][l + 64] - m);
    float e2 = expf(p[wv][l + 128] - m), e3 = expf(p[wv][l + 192] - m);
    float ssum = (e0 + e1) + (e2 + e3);
    for (int o = 32; o; o >>= 1) ssum += __shfl_xor(ssum, o);
    float inv = 1.f / ssum;
    p[wv][l] = e0 * inv; p[wv][l + 64] = e1 * inv;
    p[wv][l + 128] = e2 * inv; p[wv][l + 192] = e3 * inv;
  }
  __syncthreads();

  float ax[TDG] = {0.f, 0.f, 0.f, 0.f}, ay[TDG] = {0.f, 0.f, 0.f, 0.f};
  const float* eo = enc_out + (size_t)b * S_ * H_ + (t << 1);
  for (int i = 0; i < S_; ++i) {
    float2 v = *(const float2*)(eo + (size_t)i * H_);
    #pragma unroll
    for (int u = 0; u < TDG; ++u) {
      float pi = p[u][i];
      ax[u] += pi * v.x; ay[u] += pi * v.y;
    }
  }
  #pragma unroll
  for (int u = 0; u < TDG; ++u) {
    int td = ch * TDG + u;
    if (td < TD_) {
      float* cd = Cmat + ((size_t)td * B_ + b) * (2 * H_) + (t << 1);
      cd[0] = ax[u]; cd[1] = ay[u];
    }
  }
}

// ---------------- fc1: 64x64 fp32 GEMM, relu + bf16-split epilogue (proven) ----------------
__launch_bounds__(WGS)
__global__ void gemm64_fc1(const float* __restrict__ A,
                           const float* __restrict__ Bw,
                           const float* __restrict__ bias,
                           unsigned short* __restrict__ Ohi,
                           unsigned short* __restrict__ Olo)
{
  const int M = TD_ * B_, N = H_, K = 2 * H_;
  const int BK = 16;
  __shared__ float As[BK][64];
  __shared__ float Bs[BK][64];
  const int m0 = blockIdx.y * 64, n0 = blockIdx.x * 64;
  const int t = threadIdx.x;
  const int tx = t & 15, ty = t >> 4;
  float acc[4][4] = {{0.f}};

  const int row = t >> 2, kk = (t & 3) * 4;
  for (int k0 = 0; k0 < K; k0 += BK) {
    {
      int m = m0 + row;
      f32x4 v = {0.f, 0.f, 0.f, 0.f};
      if (m < M) v = *(const f32x4*)(A + (size_t)m * K + k0 + kk);
      As[kk][row] = v.x; As[kk + 1][row] = v.y; As[kk + 2][row] = v.z; As[kk + 3][row] = v.w;
      int n = n0 + row;
      f32x4 wv = *(const f32x4*)(Bw + (size_t)n * K + k0 + kk);
      Bs[kk][row] = wv.x; Bs[kk + 1][row] = wv.y; Bs[kk + 2][row] = wv.z; Bs[kk + 3][row] = wv.w;
    }
    __syncthreads();
    #pragma unroll
    for (int k = 0; k < BK; ++k) {
      float a[4], bq[4];
      *(f32x4*)a  = *(const f32x4*)&As[k][ty * 4];
      *(f32x4*)bq = *(const f32x4*)&Bs[k][tx * 4];
      #pragma unroll
      for (int i = 0; i < 4; ++i)
        #pragma unroll
        for (int jj = 0; jj < 4; ++jj)
          acc[i][jj] += a[i] * bq[jj];
    }
    __syncthreads();
  }

  #pragma unroll
  for (int i = 0; i < 4; ++i) {
    int m = m0 + ty * 4 + i;
    if (m >= M) continue;
    u16x4 hv, lv;
    #pragma unroll
    for (int jj = 0; jj < 4; ++jj) {
      int n = n0 + tx * 4 + jj;
      float v = fmaxf(acc[i][jj] + bias[n], 0.f);
      unsigned short hb = f2bf(v);
      hv[jj] = hb;
      lv[jj] = f2bf(v - bf2f(hb));
    }
    size_t o = (size_t)m * H_ + n0 + tx * 4;
    *(u16x4*)(Ohi + o) = hv;
    *(u16x4*)(Olo + o) = lv;
  }
}

// ---------------- fp32 -> bf16 hi/lo split (W2, proven) ----------------
__global__ __launch_bounds__(WGS)
void cvt_split(const float* __restrict__ x, unsigned short* __restrict__ hi,
               unsigned short* __restrict__ lo, int n4)
{
  int i = blockIdx.x * WGS + threadIdx.x;
  if (i >= n4) return;
  f32x4 v = *(const f32x4*)(x + (size_t)i * 4);
  u16x4 h, l;
  #pragma unroll
  for (int d = 0; d < 4; ++d) {
    unsigned short hb = f2bf(v[d]);
    h[d] = hb;
    l[d] = f2bf(v[d] - bf2f(hb));
  }
  *(u16x4*)(hi + (size_t)i * 4) = h;
  *(u16x4*)(lo + (size_t)i * 4) = l;
}

// ---------------- MFMA bf16x3 vocab projection, 256x128 tile (round-11 proven) ----------------
__global__ __launch_bounds__(WGS, 1)
void gemm_mfma_out(const unsigned short* __restrict__ Ahi,
                   const unsigned short* __restrict__ Alo,
                   const unsigned short* __restrict__ Bhi,
                   const unsigned short* __restrict__ Blo,
                   const float* __restrict__ bias,
                   float* __restrict__ out)
{
  __shared__ char smem[49152];   // Ahi 16K | Alo 16K | Bhi 8K | Blo 8K
  const int t = threadIdx.x;
  const int l = t & 63, wv = t >> 6;
  const int r = l & 15, q = l >> 4;
  const int m0 = blockIdx.x * 256;
  const int n0 = blockIdx.y * 128;
  const int M = TD_ * B_, N = VS_, K = H_;
  const int wm = (wv >> 1) * 128;
  const int wn = (wv & 1) * 64;

  int aswz[4]; size_t aoff[4];
  #pragma unroll
  for (int i = 0; i < 4; ++i) {
    int ca = i * 256 + t;
    int row = ca >> 2, cc = ca & 3;
    aswz[i] = row * 64 + ((cc ^ ((row >> 1) & 3)) << 4);
    int gm = m0 + row; if (gm >= M) gm = M - 1;
    aoff[i] = (size_t)gm * K + cc * 8;
  }
  int bswz[2]; size_t boff[2];
  #pragma unroll
  for (int i = 0; i < 2; ++i) {
    int cb = i * 256 + t;
    int row = cb >> 2, cc = cb & 3;
    bswz[i] = row * 64 + ((cc ^ ((row >> 1) & 3)) << 4);
    int gn = n0 + row; if (gn >= N) gn = N - 1;
    boff[i] = (size_t)gn * K + cc * 8;
  }

  u32x4 rg[12];
  auto gload = [&](int k0) {
    #pragma unroll
    for (int i = 0; i < 4; ++i) rg[i]     = *(const u32x4*)(Ahi + aoff[i] + k0);
    #pragma unroll
    for (int i = 0; i < 4; ++i) rg[4 + i] = *(const u32x4*)(Alo + aoff[i] + k0);
    #pragma unroll
    for (int i = 0; i < 2; ++i) rg[8 + i] = *(const u32x4*)(Bhi + boff[i] + k0);
    #pragma unroll
    for (int i = 0; i < 2; ++i) rg[10 + i] = *(const u32x4*)(Blo + boff[i] + k0);
  };
  auto swrite = [&]() {
    #pragma unroll
    for (int i = 0; i < 4; ++i) *(u32x4*)(smem + aswz[i]) = rg[i];
    #pragma unroll
    for (int i = 0; i < 4; ++i) *(u32x4*)(smem + 16384 + aswz[i]) = rg[4 + i];
    #pragma unroll
    for (int i = 0; i < 2; ++i) *(u32x4*)(smem + 32768 + bswz[i]) = rg[8 + i];
    #pragma unroll
    for (int i = 0; i < 2; ++i) *(u32x4*)(smem + 40960 + bswz[i]) = rg[10 + i];
  };

  int afo[8], bfo[4];
  #pragma unroll
  for (int fi = 0; fi < 8; ++fi) {
    int ra = wm + fi * 16 + r;
    afo[fi] = ra * 64 + ((q ^ ((ra >> 1) & 3)) << 4);
  }
  #pragma unroll
  for (int nj = 0; nj < 4; ++nj) {
    int rb = wn + nj * 16 + r;
    bfo[nj] = rb * 64 + ((q ^ ((rb >> 1) & 3)) << 4);
  }

  f32x4 acc[8][4];
  #pragma unroll
  for (int fi = 0; fi < 8; ++fi)
    #pragma unroll
    for (int nj = 0; nj < 4; ++nj) acc[fi][nj] = (f32x4){0.f, 0.f, 0.f, 0.f};

  gload(0);
  swrite();
  __syncthreads();
  const int NS = K / 32;   // 16
  for (int s = 0; s < NS; ++s) {
    if (s + 1 < NS) gload((s + 1) * 32);
    s16x8 bh[4], bl[4];
    #pragma unroll
    for (int nj = 0; nj < 4; ++nj) {
      bh[nj] = *(const s16x8*)(smem + 32768 + bfo[nj]);
      bl[nj] = *(const s16x8*)(smem + 40960 + bfo[nj]);
    }
    #pragma unroll
    for (int fi = 0; fi < 8; ++fi) {
      s16x8 ah = *(const s16x8*)(smem + afo[fi]);
      s16x8 al = *(const s16x8*)(smem + 16384 + afo[fi]);
      #pragma unroll
      for (int nj = 0; nj < 4; ++nj) {
        acc[fi][nj] = __builtin_amdgcn_mfma_f32_16x16x32_bf16(ah, bh[nj], acc[fi][nj], 0, 0, 0);
        acc[fi][nj] = __builtin_amdgcn_mfma_f32_16x16x32_bf16(ah, bl[nj], acc[fi][nj], 0, 0, 0);
        acc[fi][nj] = __builtin_amdgcn_mfma_f32_16x16x32_bf16(al, bh[nj], acc[fi][nj], 0, 0, 0);
      }
    }
    __syncthreads();
    if (s + 1 < NS) { swrite(); __syncthreads(); }
  }

  #pragma unroll
  for (int nj = 0; nj < 4; ++nj) {
    int n = n0 + wn + nj * 16 + r;
    if (n >= N) continue;
    float bv = bias[n];
    #pragma unroll
    for (int fi = 0; fi < 8; ++fi) {
      #pragma unroll
      for (int e = 0; e < 4; ++e) {
        int m = m0 + wm + fi * 16 + q * 4 + e;
        if (m < M) {
          int bidx = m & 31, td = m >> 5;
          out[((size_t)bidx * TD_ + td) * (size_t)N + n] = acc[fi][nj][e] + bv;
        }
      }
    }
  }
}

// ---------------- launch ----------------
extern "C" void kernel_launch(void* const* d_in, const int* in_sizes, int n_in,
                              void* d_out, int out_size, void* d_ws, size_t ws_size,
                              hipStream_t stream) {
  const int*   method_code    = (const int*)d_in[0];
  const int*   method_summary = (const int*)d_in[1];
  const float* enc_emb = (const float*)d_in[3];
  const float* enc_Wih = (const float*)d_in[4];
  const float* enc_Whh = (const float*)d_in[5];
  const float* enc_bih = (const float*)d_in[6];
  const float* enc_bhh = (const float*)d_in[7];
  const float* dec_emb = (const float*)d_in[8];
  const float* dec_Wih = (const float*)d_in[9];
  const float* dec_Whh = (const float*)d_in[10];
  const float* dec_bih = (const float*)d_in[11];
  const float* dec_bhh = (const float*)d_in[12];
  const float* W1 = (const float*)d_in[13];
  const float* b1 = (const float*)d_in[14];
  const float* W2 = (const float*)d_in[15];
  const float* b2 = (const float*)d_in[16];

  float* ws      = (float*)d_ws;
  float* enc_out = ws + OFF_ENC_OUT;
  float* hbuf    = ws + OFF_HBUF;
  float* Cmat    = ws + OFF_CMAT;
  unsigned short* W2hi = (unsigned short*)(ws + OFF_W2HI);
  unsigned short* W2lo = (unsigned short*)(ws + OFF_W2LO);
  unsigned short* O1hi = (unsigned short*)(ws + OFF_O1HI);
  unsigned short* O1lo = (unsigned short*)(ws + OFF_O1LO);

  // reset exchange buffers (tags=0 == h_0 valid, payload zeros) every call
  hipMemsetAsync(hbuf, 0, SZ_HBUF * sizeof(float), stream);

  dim3 blk(WGS);

  // persistent GRU chains: 16 domains x 16 j-groups, tagged-line exchange
  recurrence_kernel<<<NWGR, blk, 0, stream>>>(
      method_code, method_summary,
      enc_emb, enc_Wih, enc_bih,
      dec_emb, dec_Wih, dec_bih,
      enc_Whh, enc_bhh, dec_Whh, dec_bhh,
      enc_out, hbuf, Cmat);

  // attention: 4 td per WG, 416 WGs
  attention_kernel<<<B_ * 13, blk, 0, stream>>>(enc_out, Cmat);

  // W2 bf16 split (overlays now-dead enc_out region; runs after attention)
  cvt_split<<<(VS_ * H_ / 4 + WGS - 1) / WGS, blk, 0, stream>>>(
      W2, W2hi, W2lo, VS_ * H_ / 4);

  // fc1: relu(Cmat @ W1^T + b1) -> bf16 hi/lo, 200 WGs
  gemm64_fc1<<<dim3(H_ / 64, (TD_ * B_ + 63) / 64), blk, 0, stream>>>(
      Cmat, W1, b1, O1hi, O1lo);

  // vocab projection via 3-term bf16 MFMA, 256x128 tile
  gemm_mfma_out<<<dim3((TD_ * B_ + 255) / 256, (VS_ + 127) / 128), blk, 0, stream>>>(
      O1hi, O1lo, W2hi, W2lo, b2, (float*)d_out);
}